// Round 15
// baseline (252.324 us; speedup 1.0000x reference)
//
#include <hip/hip_runtime.h>
#include <hip/hip_bf16.h>
#include <stdint.h>

#define Bb 4
#define Ss 2048
#define Dd 1024
#define Hh 16
#define DK 64
#define BH 64
#define Mm 8192
#define KVT 64

typedef __attribute__((ext_vector_type(8))) _Float16 f16x8;
typedef __attribute__((ext_vector_type(4))) _Float16 f16x4;
typedef __attribute__((ext_vector_type(2))) __fp16 fp16x2;
typedef __attribute__((ext_vector_type(4))) float f32x4;
typedef __attribute__((ext_vector_type(16))) float f32x16;
typedef __attribute__((ext_vector_type(2))) unsigned uint2v;

__device__ __forceinline__ void gload16(const _Float16* g, _Float16* lds) {
  __builtin_amdgcn_global_load_lds((const __attribute__((address_space(1))) unsigned int*)g,
                                   (__attribute__((address_space(3))) unsigned int*)lds, 16, 0, 0);
}

// single v_exp_f32 (2^x). exp2f() is the libm path — the r11 regression.
#if __has_builtin(__builtin_amdgcn_exp2f)
__device__ __forceinline__ float ex2(float x) { return __builtin_amdgcn_exp2f(x); }
#else
__device__ __forceinline__ float ex2(float x) {
  float r; asm("v_exp_f32 %0, %1" : "=v"(r) : "v"(x)); return r;
}
#endif

// pack two f32 -> u32 of 2 f16 (v_cvt_pkrtz_f16_f32, 1 inst)
__device__ __forceinline__ unsigned pk2u(float a, float b) {
  union { fp16x2 h; unsigned u; } x;
  x.h = __builtin_amdgcn_cvt_pkrtz(a, b);
  return x.u;
}

// ---------------- K0a: convert activations fp32 -> fp16 ----------------
__global__ __launch_bounds__(256) void cvt_act(const float* __restrict__ q,
                                               const float* __restrict__ k,
                                               const float* __restrict__ v,
                                               _Float16* __restrict__ xq,
                                               _Float16* __restrict__ xk,
                                               _Float16* __restrict__ xv) {
  const float* src = blockIdx.z == 0 ? q : (blockIdx.z == 1 ? k : v);
  _Float16* dst = blockIdx.z == 0 ? xq : (blockIdx.z == 1 ? xk : xv);
  int i = (blockIdx.x * 256 + threadIdx.x) * 8;
  float4 a = *(const float4*)(src + i);
  float4 b = *(const float4*)(src + i + 4);
  union { f16x8 v8; _Float16 h[8]; } o;
  o.h[0] = (_Float16)a.x; o.h[1] = (_Float16)a.y; o.h[2] = (_Float16)a.z; o.h[3] = (_Float16)a.w;
  o.h[4] = (_Float16)b.x; o.h[5] = (_Float16)b.y; o.h[6] = (_Float16)b.z; o.h[7] = (_Float16)b.w;
  *(f16x8*)(dst + i) = o.v8;
}

// ---------------- K0b: convert + transpose weights: Wt[n][k] = f16(W[k][n]) ----------------
// Q weights pre-scaled by log2(e): attention scores land in the exp2 domain.
__global__ __launch_bounds__(256) void cvt_wt(const float* __restrict__ wq,
                                              const float* __restrict__ wk,
                                              const float* __restrict__ wv,
                                              _Float16* __restrict__ tq,
                                              _Float16* __restrict__ tk,
                                              _Float16* __restrict__ tv) {
  const float* w = blockIdx.z == 0 ? wq : (blockIdx.z == 1 ? wk : wv);
  _Float16* o = blockIdx.z == 0 ? tq : (blockIdx.z == 1 ? tk : tv);
  float wscale = blockIdx.z == 0 ? 1.4426950408889634f : 1.0f;
  __shared__ float tile[64][65];
  int k0 = blockIdx.x * 64;
  int n0 = blockIdx.y * 64;
  int t = threadIdx.x;
  int tr = t >> 4;
  int tc = (t & 15) * 4;
  for (int i = 0; i < 4; i++) {
    int r = i * 16 + tr;
    float4 val = *(const float4*)(w + (k0 + r) * Dd + n0 + tc);
    tile[r][tc + 0] = val.x; tile[r][tc + 1] = val.y;
    tile[r][tc + 2] = val.z; tile[r][tc + 3] = val.w;
  }
  __syncthreads();
  for (int i = 0; i < 2; i++) {
    int vdx = t + 256 * i;
    int rn = vdx >> 3;
    int c8 = (vdx & 7) * 8;
    union { f16x8 v8; _Float16 h[8]; } o2;
    for (int j = 0; j < 8; j++) o2.h[j] = (_Float16)(tile[c8 + j][rn] * wscale);
    *(f16x8*)(o + (n0 + rn) * Dd + k0 + c8) = o2.v8;
  }
}

// ---------------- K1: projection GEMM (m97 structure) ----------------
// Q,K outputs in [bh][s][dk]; V output written TRANSPOSED [bh][dk][s].
__global__ __launch_bounds__(256) void gemm_qkv(
    const _Float16* __restrict__ xq, const _Float16* __restrict__ xk,
    const _Float16* __restrict__ xv,
    const _Float16* __restrict__ wtq, const _Float16* __restrict__ wtk,
    const _Float16* __restrict__ wtv,
    const float* __restrict__ bq, const float* __restrict__ bk, const float* __restrict__ bv,
    _Float16* __restrict__ oq, _Float16* __restrict__ ok,
    _Float16* __restrict__ ov) {
  int z = blockIdx.z;
  const _Float16* A  = z == 0 ? xq  : (z == 1 ? xk  : xv);
  const _Float16* Bt = z == 0 ? wtq : (z == 1 ? wtk : wtv);
  const float* bias  = z == 0 ? bq  : (z == 1 ? bk  : bv);
  _Float16* out      = z == 0 ? oq  : (z == 1 ? ok  : ov);
  float bscale       = z == 0 ? 1.4426950408889634f : 1.0f;

  __shared__ _Float16 As[128 * 64];
  __shared__ _Float16 Bs[128 * 64];

  int tid = threadIdx.x;
  int w = tid >> 6;
  int l = tid & 63;
  int lr = l & 15, lk = l >> 4;
  int m0 = blockIdx.x * 128;
  int n0 = blockIdx.y * 128;
  int wr = (w >> 1) * 64;
  int wc = (w & 1) * 64;

  f32x4 acc[4][4] = {};

  for (int kt = 0; kt < Dd; kt += 64) {
    __syncthreads();
    for (int i = 0; i < 4; i++) {
      int fbase = i * 256 + w * 64;     // wave-uniform chunk base
      int f = fbase + l;
      int r = f >> 3, c = (f & 7) * 8;
      gload16(A + (m0 + r) * Dd + kt + c, &As[fbase * 8]);
      gload16(Bt + (n0 + r) * Dd + kt + c, &Bs[fbase * 8]);
    }
    __syncthreads();
    for (int kh = 0; kh < 2; kh++) {
      f16x8 af[4], bfr[4];
      for (int mi = 0; mi < 4; mi++)
        af[mi] = *(const f16x8*)&As[(wr + mi * 16 + lr) * 64 + kh * 32 + lk * 8];
      for (int ni = 0; ni < 4; ni++)
        bfr[ni] = *(const f16x8*)&Bs[(wc + ni * 16 + lr) * 64 + kh * 32 + lk * 8];
      for (int mi = 0; mi < 4; mi++)
        for (int ni = 0; ni < 4; ni++)
          acc[mi][ni] = __builtin_amdgcn_mfma_f32_16x16x32_f16(af[mi], bfr[ni], acc[mi][ni], 0, 0, 0);
    }
  }

  if (z == 2) {
    // V^T epilogue: lane holds 4 consecutive s for fixed dk -> one aligned 8B store
    for (int mi = 0; mi < 4; mi++) {
      for (int ni = 0; ni < 4; ni++) {
        int n = n0 + wc + ni * 16 + lr;
        float bval = bias[n];
        int h = n >> 6, dk = n & 63;
        int m = m0 + wr + mi * 16 + lk * 4;
        int b = m >> 11, s = m & 2047;
        f16x4 o4;
        for (int j = 0; j < 4; j++) o4[j] = (_Float16)(acc[mi][ni][j] + bval);
        *(f16x4*)(out + ((size_t)((b * Hh + h) * DK + dk) * Ss + s)) = o4;
      }
    }
  } else {
    for (int mi = 0; mi < 4; mi++) {
      for (int ni = 0; ni < 4; ni++) {
        int n = n0 + wc + ni * 16 + lr;
        float bval = bias[n] * bscale;
        int h = n >> 6, dk = n & 63;
        for (int j = 0; j < 4; j++) {
          int m = m0 + wr + mi * 16 + lk * 4 + j;
          int b = m >> 11, s = m & 2047;
          out[((b * Hh + h) * Ss + s) * DK + dk] = (_Float16)(acc[mi][ni][j] + bval);
        }
      }
    }
  }
}

// ---------------- K3: flash attention, 32x32x16, 64 q-rows/wave (2 q-groups) ----------------
// Q,K: [bh][s][64] f16 (Q pre-scaled by log2e); Vt: [bh][64][s] f16; out fp32 = ctx + query.
// 512 blocks x 4 waves; wave owns 64 q-rows as two 32-col groups A/B sharing one K/V LDS
// read stream (LDS traffic per q-row HALVED vs r14). kv-tile 64 double-buffered via
// global_load_lds DMA. Row-sum computed by ones-MFMA (matrix pipe) instead of VALU tree;
// sum fragment is complete per lane (pf merges halves) so no epilogue shfl.
__global__ __launch_bounds__(256) void attn(const _Float16* __restrict__ Qb,
                                            const _Float16* __restrict__ Kb,
                                            const _Float16* __restrict__ Vt,
                                            const float* __restrict__ query,
                                            float* __restrict__ outp) {
  __shared__ _Float16 Kl[2][KVT * 64];
  __shared__ _Float16 Vl[2][KVT * 64];

  int tid = threadIdx.x;
  int w = tid >> 6, l = tid & 63;
  int l31 = l & 31, hi = l >> 5;
  int bh = blockIdx.x;
  int q0 = blockIdx.y * 256 + w * 64;
  const _Float16* Qp = Qb + bh * (Ss * DK);
  const _Float16* Kp = Kb + bh * (Ss * DK);
  const _Float16* Vp = Vt + bh * (DK * Ss);

  // staging: lane l -> row base+(l>>3), LDS slot l&7; global slot = (l&7)^(row&7)
  int srow = l >> 3;
  int sslot = (l & 7) ^ (srow & 7);
  int w16 = w * 16;
  const _Float16* ksrc0 = Kp + (w16 + srow) * DK + sslot * 8;
  const _Float16* ksrc1 = Kp + (w16 + 8 + srow) * DK + sslot * 8;
  const _Float16* vsrc0 = Vp + (w16 + srow) * Ss + sslot * 8;
  const _Float16* vsrc1 = Vp + (w16 + 8 + srow) * Ss + sslot * 8;

#define STAGE(KV0, BUF)                                                   \
  {                                                                       \
    gload16(ksrc0 + (KV0) * DK, &Kl[BUF][w16 * 64]);                      \
    gload16(ksrc1 + (KV0) * DK, &Kl[BUF][(w16 + 8) * 64]);                \
    gload16(vsrc0 + (KV0), &Vl[BUF][w16 * 64]);                           \
    gload16(vsrc1 + (KV0), &Vl[BUF][(w16 + 8) * 64]);                     \
  }

  // Q fragments for both q-groups: col q = q0 + qg*32 + l31, k = s*16 + hi*8
  f16x8 qfA[4], qfB[4];
#pragma unroll
  for (int s = 0; s < 4; s++) {
    qfA[s] = *(const f16x8*)(Qp + (q0 + l31) * DK + s * 16 + hi * 8);
    qfB[s] = *(const f16x8*)(Qp + (q0 + 32 + l31) * DK + s * 16 + hi * 8);
  }

  // ones fragment for the row-sum MFMA
  f16x8 ones;
#pragma unroll
  for (int j = 0; j < 8; j++) ones[j] = (_Float16)1.0f;

  f32x16 oA0 = {}, oA1 = {}, oB0 = {}, oB1 = {};   // ctx^T per group per d-half
  f32x16 smA = {}, smB = {};                        // row-sum accumulators (all rows equal)
  float mrunA = -1e30f, mrunB = -1e30f;

  int kv7 = l31 & 7;
  int rslot[4];
#pragma unroll
  for (int s = 0; s < 4; s++) rslot[s] = ((s * 2 + hi) ^ kv7) * 8;

  STAGE(0, 0)
  __syncthreads();

  int cur = 0;
  for (int kv0 = 0; kv0 < Ss; kv0 += KVT) {
    if (kv0 + KVT < Ss) STAGE(kv0 + KVT, cur ^ 1)

    // ---- QK^T both groups, K read ONCE from LDS ----
    const _Float16* Kc = &Kl[cur][0];
    f32x16 sA0 = {}, sA1 = {}, sB0 = {}, sB1 = {};
#pragma unroll
    for (int s = 0; s < 4; s++) {
      f16x8 ka = *(const f16x8*)&Kc[l31 * 64 + rslot[s]];
      f16x8 kb = *(const f16x8*)&Kc[(32 + l31) * 64 + rslot[s]];
      sA0 = __builtin_amdgcn_mfma_f32_32x32x16_f16(ka, qfA[s], sA0, 0, 0, 0);
      sA1 = __builtin_amdgcn_mfma_f32_32x32x16_f16(kb, qfA[s], sA1, 0, 0, 0);
      sB0 = __builtin_amdgcn_mfma_f32_32x32x16_f16(ka, qfB[s], sB0, 0, 0, 0);
      sB1 = __builtin_amdgcn_mfma_f32_32x32x16_f16(kb, qfB[s], sB1, 0, 0, 0);
    }

    // ---- lane-local online softmax per group (exp2 domain, defer-max) ----
#define SOFTMAX(S0, S1, MRUN, O0, O1, SM)                                       \
    {                                                                           \
      float m8[8];                                                              \
      _Pragma("unroll")                                                         \
      for (int r = 0; r < 8; r++)                                               \
        m8[r] = fmaxf(fmaxf(S0[r], S0[r + 8]), fmaxf(S1[r], S1[r + 8]));        \
      _Pragma("unroll")                                                         \
      for (int d = 4; d >= 1; d >>= 1)                                          \
        for (int r = 0; r < 4; r++) if (r < d) m8[r] = fmaxf(m8[r], m8[r + d]); \
      float pm = fmaxf(m8[0], __shfl_xor(m8[0], 32));                           \
      if (!__all(pm - MRUN <= 8.f)) {                                           \
        float mn = fmaxf(MRUN, pm);                                             \
        float sc_ = ex2(MRUN - mn);                                             \
        MRUN = mn;                                                              \
        _Pragma("unroll")                                                       \
        for (int r = 0; r < 16; r++) {                                          \
          O0[r] *= sc_; O1[r] *= sc_; SM[r] *= sc_;                             \
        }                                                                       \
      }                                                                         \
      _Pragma("unroll")                                                         \
      for (int r = 0; r < 16; r++) {                                            \
        S0[r] = ex2(S0[r] - MRUN);                                              \
        S1[r] = ex2(S1[r] - MRUN);                                              \
      }                                                                         \
    }
    SOFTMAX(sA0, sA1, mrunA, oA0, oA1, smA)
    SOFTMAX(sB0, sB1, mrunB, oB0, oB1, smB)
#undef SOFTMAX

    // ---- PV + ones-sum: V read ONCE per kstep, used by both groups ----
    const _Float16* Vc = &Vl[cur][0];
#define PVSTEP(SA, SB, OFF, KST)                                                \
    {                                                                           \
      f16x8 v0 = *(const f16x8*)&Vc[l31 * 64 + rslot[KST]];                     \
      f16x8 v1 = *(const f16x8*)&Vc[(32 + l31) * 64 + rslot[KST]];              \
      unsigned aa0 = pk2u(SA[(OFF) + 0], SA[(OFF) + 1]);                        \
      unsigned aa1 = pk2u(SA[(OFF) + 2], SA[(OFF) + 3]);                        \
      unsigned ab0 = pk2u(SA[(OFF) + 4], SA[(OFF) + 5]);                        \
      unsigned ab1 = pk2u(SA[(OFF) + 6], SA[(OFF) + 7]);                        \
      uint2v ra0 = __builtin_amdgcn_permlane32_swap(aa0, ab0, false, false);    \
      uint2v ra1 = __builtin_amdgcn_permlane32_swap(aa1, ab1, false, false);    \
      union { unsigned u[4]; f16x8 v; } pfA;                                    \
      pfA.u[0] = ra0[0]; pfA.u[1] = ra1[0]; pfA.u[2] = ra0[1]; pfA.u[3] = ra1[1];\
      unsigned ba0 = pk2u(SB[(OFF) + 0], SB[(OFF) + 1]);                        \
      unsigned ba1 = pk2u(SB[(OFF) + 2], SB[(OFF) + 3]);                        \
      unsigned bb0 = pk2u(SB[(OFF) + 4], SB[(OFF) + 5]);                        \
      unsigned bb1 = pk2u(SB[(OFF) + 6], SB[(OFF) + 7]);                        \
      uint2v rb0 = __builtin_amdgcn_permlane32_swap(ba0, bb0, false, false);    \
      uint2v rb1 = __builtin_amdgcn_permlane32_swap(ba1, bb1, false, false);    \
      union { unsigned u[4]; f16x8 v; } pfB;                                    \
      pfB.u[0] = rb0[0]; pfB.u[1] = rb1[0]; pfB.u[2] = rb0[1]; pfB.u[3] = rb1[1];\
      oA0 = __builtin_amdgcn_mfma_f32_32x32x16_f16(v0, pfA.v, oA0, 0, 0, 0);    \
      oA1 = __builtin_amdgcn_mfma_f32_32x32x16_f16(v1, pfA.v, oA1, 0, 0, 0);    \
      oB0 = __builtin_amdgcn_mfma_f32_32x32x16_f16(v0, pfB.v, oB0, 0, 0, 0);    \
      oB1 = __builtin_amdgcn_mfma_f32_32x32x16_f16(v1, pfB.v, oB1, 0, 0, 0);    \
      smA = __builtin_amdgcn_mfma_f32_32x32x16_f16(ones, pfA.v, smA, 0, 0, 0);  \
      smB = __builtin_amdgcn_mfma_f32_32x32x16_f16(ones, pfB.v, smB, 0, 0, 0);  \
    }
    PVSTEP(sA0, sB0, 0, 0)
    PVSTEP(sA0, sB0, 8, 1)
    PVSTEP(sA1, sB1, 0, 2)
    PVSTEP(sA1, sB1, 8, 3)
#undef PVSTEP

    __syncthreads();   // reads of buf[cur] done; staging of buf[cur^1] drained
    cur ^= 1;
  }

  // ---- epilogue: sum accumulators are complete per lane (pf merged halves) ----
  int b = bh >> 4, h = bh & 15;
#define WRITEOUT(O0, O1, SM, QOFF)                                              \
  {                                                                             \
    float inv = 1.f / SM[0];                                                    \
    int base = (b * Ss + q0 + (QOFF) + l31) * Dd + h * 64;                      \
    _Pragma("unroll")                                                           \
    for (int rq = 0; rq < 4; rq++) {                                            \
      int d0 = rq * 8 + hi * 4;                                                 \
      float4 qv0 = *(const float4*)(query + base + d0);                         \
      float4 ov0;                                                               \
      ov0.x = O0[rq * 4 + 0] * inv + qv0.x;                                     \
      ov0.y = O0[rq * 4 + 1] * inv + qv0.y;                                     \
      ov0.z = O0[rq * 4 + 2] * inv + qv0.z;                                     \
      ov0.w = O0[rq * 4 + 3] * inv + qv0.w;                                     \
      *(float4*)(outp + base + d0) = ov0;                                       \
      float4 qv1 = *(const float4*)(query + base + 32 + d0);                    \
      float4 ov1;                                                               \
      ov1.x = O1[rq * 4 + 0] * inv + qv1.x;                                     \
      ov1.y = O1[rq * 4 + 1] * inv + qv1.y;                                     \
      ov1.z = O1[rq * 4 + 2] * inv + qv1.z;                                     \
      ov1.w = O1[rq * 4 + 3] * inv + qv1.w;                                     \
      *(float4*)(outp + base + 32 + d0) = ov1;                                  \
    }                                                                           \
  }
  WRITEOUT(oA0, oA1, smA, 0)
  WRITEOUT(oB0, oB1, smB, 32)
#undef WRITEOUT
#undef STAGE
}

extern "C" void kernel_launch(void* const* d_in, const int* in_sizes, int n_in,
                              void* d_out, int out_size, void* d_ws, size_t ws_size,
                              hipStream_t stream) {
  const float* query = (const float*)d_in[0];
  const float* key   = (const float*)d_in[1];
  const float* value = (const float*)d_in[2];
  const float* Wq = (const float*)d_in[3];
  const float* bq = (const float*)d_in[4];
  const float* Wk = (const float*)d_in[5];
  const float* bk = (const float*)d_in[6];
  const float* Wv = (const float*)d_in[7];
  const float* bv = (const float*)d_in[8];
  float* out = (float*)d_out;

  _Float16* ws = (_Float16*)d_ws;
  const size_t ACT = (size_t)Mm * Dd;
  const size_t WSZ = (size_t)Dd * Dd;
  _Float16* Xq   = ws;
  _Float16* Xk   = Xq + ACT;
  _Float16* Xv   = Xk + ACT;
  _Float16* Wtq  = Xv + ACT;
  _Float16* Wtk  = Wtq + WSZ;
  _Float16* Wtv  = Wtk + WSZ;
  _Float16* Qb   = Wtv + WSZ;
  _Float16* Kb   = Qb + ACT;
  _Float16* VtT  = Kb + ACT;   // gemm writes V^T [bh][dk][s] here directly

  cvt_act<<<dim3(4096, 1, 3), dim3(256), 0, stream>>>(query, key, value, Xq, Xk, Xv);
  cvt_wt<<<dim3(16, 16, 3), dim3(256), 0, stream>>>(Wq, Wk, Wv, Wtq, Wtk, Wtv);
  gemm_qkv<<<dim3(64, 8, 3), dim3(256), 0, stream>>>(Xq, Xk, Xv, Wtq, Wtk, Wtv,
                                                     bq, bk, bv, Qb, Kb, VtT);
  attn<<<dim3(64, 8), dim3(256), 0, stream>>>(Qb, Kb, VtT, query, out);
}

// Round 16
// 220.253 us; speedup vs baseline: 1.1456x; 1.1456x over previous
//
#include <hip/hip_runtime.h>
#include <hip/hip_bf16.h>
#include <stdint.h>

#define Bb 4
#define Ss 2048
#define Dd 1024
#define Hh 16
#define DK 64
#define BH 64
#define Mm 8192
#define KVT 64

typedef __attribute__((ext_vector_type(8))) _Float16 f16x8;
typedef __attribute__((ext_vector_type(4))) _Float16 f16x4;
typedef __attribute__((ext_vector_type(2))) __fp16 fp16x2;
typedef __attribute__((ext_vector_type(4))) float f32x4;
typedef __attribute__((ext_vector_type(16))) float f32x16;
typedef __attribute__((ext_vector_type(2))) unsigned uint2v;

__device__ __forceinline__ void gload16(const _Float16* g, _Float16* lds) {
  __builtin_amdgcn_global_load_lds((const __attribute__((address_space(1))) unsigned int*)g,
                                   (__attribute__((address_space(3))) unsigned int*)lds, 16, 0, 0);
}

// single v_exp_f32 (2^x). exp2f() is the libm path — the r11 regression.
#if __has_builtin(__builtin_amdgcn_exp2f)
__device__ __forceinline__ float ex2(float x) { return __builtin_amdgcn_exp2f(x); }
#else
__device__ __forceinline__ float ex2(float x) {
  float r; asm("v_exp_f32 %0, %1" : "=v"(r) : "v"(x)); return r;
}
#endif

// pack two f32 -> u32 of 2 f16 (v_cvt_pkrtz_f16_f32, 1 inst)
__device__ __forceinline__ unsigned pk2u(float a, float b) {
  union { fp16x2 h; unsigned u; } x;
  x.h = __builtin_amdgcn_cvt_pkrtz(a, b);
  return x.u;
}

// cross-half (lane ^ 32) max via permlane32_swap: VALU, not ds_bpermute (m255: 1.2x).
// r = swap(x,x): r0 = lo:own/hi:partner, r1 = lo:partner/hi:own -> fmax over both = max(own,partner).
__device__ __forceinline__ float xhalf_max(float x) {
  union { float f; unsigned u; } a; a.f = x;
  uint2v r = __builtin_amdgcn_permlane32_swap(a.u, a.u, false, false);
  union { unsigned u; float f; } b0, b1; b0.u = r[0]; b1.u = r[1];
  return fmaxf(fmaxf(x, b0.f), b1.f);
}

// ---------------- K0a: convert activations fp32 -> fp16 ----------------
__global__ __launch_bounds__(256) void cvt_act(const float* __restrict__ q,
                                               const float* __restrict__ k,
                                               const float* __restrict__ v,
                                               _Float16* __restrict__ xq,
                                               _Float16* __restrict__ xk,
                                               _Float16* __restrict__ xv) {
  const float* src = blockIdx.z == 0 ? q : (blockIdx.z == 1 ? k : v);
  _Float16* dst = blockIdx.z == 0 ? xq : (blockIdx.z == 1 ? xk : xv);
  int i = (blockIdx.x * 256 + threadIdx.x) * 8;
  float4 a = *(const float4*)(src + i);
  float4 b = *(const float4*)(src + i + 4);
  union { f16x8 v8; _Float16 h[8]; } o;
  o.h[0] = (_Float16)a.x; o.h[1] = (_Float16)a.y; o.h[2] = (_Float16)a.z; o.h[3] = (_Float16)a.w;
  o.h[4] = (_Float16)b.x; o.h[5] = (_Float16)b.y; o.h[6] = (_Float16)b.z; o.h[7] = (_Float16)b.w;
  *(f16x8*)(dst + i) = o.v8;
}

// ---------------- K0b: convert + transpose weights: Wt[n][k] = f16(W[k][n]) ----------------
// Q weights pre-scaled by log2(e): attention scores land in the exp2 domain.
__global__ __launch_bounds__(256) void cvt_wt(const float* __restrict__ wq,
                                              const float* __restrict__ wk,
                                              const float* __restrict__ wv,
                                              _Float16* __restrict__ tq,
                                              _Float16* __restrict__ tk,
                                              _Float16* __restrict__ tv) {
  const float* w = blockIdx.z == 0 ? wq : (blockIdx.z == 1 ? wk : wv);
  _Float16* o = blockIdx.z == 0 ? tq : (blockIdx.z == 1 ? tk : tv);
  float wscale = blockIdx.z == 0 ? 1.4426950408889634f : 1.0f;
  __shared__ float tile[64][65];
  int k0 = blockIdx.x * 64;
  int n0 = blockIdx.y * 64;
  int t = threadIdx.x;
  int tr = t >> 4;
  int tc = (t & 15) * 4;
  for (int i = 0; i < 4; i++) {
    int r = i * 16 + tr;
    float4 val = *(const float4*)(w + (k0 + r) * Dd + n0 + tc);
    tile[r][tc + 0] = val.x; tile[r][tc + 1] = val.y;
    tile[r][tc + 2] = val.z; tile[r][tc + 3] = val.w;
  }
  __syncthreads();
  for (int i = 0; i < 2; i++) {
    int vdx = t + 256 * i;
    int rn = vdx >> 3;
    int c8 = (vdx & 7) * 8;
    union { f16x8 v8; _Float16 h[8]; } o2;
    for (int j = 0; j < 8; j++) o2.h[j] = (_Float16)(tile[c8 + j][rn] * wscale);
    *(f16x8*)(o + (n0 + rn) * Dd + k0 + c8) = o2.v8;
  }
}

// ---------------- K1: projection GEMM (m97 structure) ----------------
// Q,K outputs in [bh][s][dk]; V output written TRANSPOSED [bh][dk][s].
__global__ __launch_bounds__(256) void gemm_qkv(
    const _Float16* __restrict__ xq, const _Float16* __restrict__ xk,
    const _Float16* __restrict__ xv,
    const _Float16* __restrict__ wtq, const _Float16* __restrict__ wtk,
    const _Float16* __restrict__ wtv,
    const float* __restrict__ bq, const float* __restrict__ bk, const float* __restrict__ bv,
    _Float16* __restrict__ oq, _Float16* __restrict__ ok,
    _Float16* __restrict__ ov) {
  int z = blockIdx.z;
  const _Float16* A  = z == 0 ? xq  : (z == 1 ? xk  : xv);
  const _Float16* Bt = z == 0 ? wtq : (z == 1 ? wtk : wtv);
  const float* bias  = z == 0 ? bq  : (z == 1 ? bk  : bv);
  _Float16* out      = z == 0 ? oq  : (z == 1 ? ok  : ov);
  float bscale       = z == 0 ? 1.4426950408889634f : 1.0f;

  __shared__ _Float16 As[128 * 64];
  __shared__ _Float16 Bs[128 * 64];

  int tid = threadIdx.x;
  int w = tid >> 6;
  int l = tid & 63;
  int lr = l & 15, lk = l >> 4;
  int m0 = blockIdx.x * 128;
  int n0 = blockIdx.y * 128;
  int wr = (w >> 1) * 64;
  int wc = (w & 1) * 64;

  f32x4 acc[4][4] = {};

  for (int kt = 0; kt < Dd; kt += 64) {
    __syncthreads();
    for (int i = 0; i < 4; i++) {
      int fbase = i * 256 + w * 64;     // wave-uniform chunk base
      int f = fbase + l;
      int r = f >> 3, c = (f & 7) * 8;
      gload16(A + (m0 + r) * Dd + kt + c, &As[fbase * 8]);
      gload16(Bt + (n0 + r) * Dd + kt + c, &Bs[fbase * 8]);
    }
    __syncthreads();
    for (int kh = 0; kh < 2; kh++) {
      f16x8 af[4], bfr[4];
      for (int mi = 0; mi < 4; mi++)
        af[mi] = *(const f16x8*)&As[(wr + mi * 16 + lr) * 64 + kh * 32 + lk * 8];
      for (int ni = 0; ni < 4; ni++)
        bfr[ni] = *(const f16x8*)&Bs[(wc + ni * 16 + lr) * 64 + kh * 32 + lk * 8];
      for (int mi = 0; mi < 4; mi++)
        for (int ni = 0; ni < 4; ni++)
          acc[mi][ni] = __builtin_amdgcn_mfma_f32_16x16x32_f16(af[mi], bfr[ni], acc[mi][ni], 0, 0, 0);
    }
  }

  if (z == 2) {
    // V^T epilogue: lane holds 4 consecutive s for fixed dk -> one aligned 8B store
    for (int mi = 0; mi < 4; mi++) {
      for (int ni = 0; ni < 4; ni++) {
        int n = n0 + wc + ni * 16 + lr;
        float bval = bias[n];
        int h = n >> 6, dk = n & 63;
        int m = m0 + wr + mi * 16 + lk * 4;
        int b = m >> 11, s = m & 2047;
        f16x4 o4;
        for (int j = 0; j < 4; j++) o4[j] = (_Float16)(acc[mi][ni][j] + bval);
        *(f16x4*)(out + ((size_t)((b * Hh + h) * DK + dk) * Ss + s)) = o4;
      }
    }
  } else {
    for (int mi = 0; mi < 4; mi++) {
      for (int ni = 0; ni < 4; ni++) {
        int n = n0 + wc + ni * 16 + lr;
        float bval = bias[n] * bscale;
        int h = n >> 6, dk = n & 63;
        for (int j = 0; j < 4; j++) {
          int m = m0 + wr + mi * 16 + lk * 4 + j;
          int b = m >> 11, s = m & 2047;
          out[((b * Hh + h) * Ss + s) * DK + dk] = (_Float16)(acc[mi][ni][j] + bval);
        }
      }
    }
  }
}

// ---------------- K3: flash attention, 32x32x16, LDS double-buffered K/V (r14 design) ----------------
// Q,K: [bh][s][64] f16 (Q pre-scaled by log2e); Vt: [bh][64][s] f16; out fp32 = ctx + query.
// 1024 blocks x 4 waves, 32 q-rows/wave. kv-tile 64 double-buffered via global_load_lds DMA
// (the only staging mechanism this compiler reliably pipelines — r5/6/8/9/10 evidence).
// Softmax: exp2 domain, ONE v_exp_f32 per P; cross-half max via permlane32_swap (VALU, not
// ds_bpermute — keeps it off the contended LDS pipe). lrun lane-partial (epilogue reduce).
// No setprio (4-wave lockstep = T5-negative regime, m190).
__global__ __launch_bounds__(256) void attn(const _Float16* __restrict__ Qb,
                                            const _Float16* __restrict__ Kb,
                                            const _Float16* __restrict__ Vt,
                                            const float* __restrict__ query,
                                            float* __restrict__ outp) {
  __shared__ _Float16 Kl[2][KVT * 64];
  __shared__ _Float16 Vl[2][KVT * 64];

  int tid = threadIdx.x;
  int w = tid >> 6, l = tid & 63;
  int l31 = l & 31, hi = l >> 5;
  int bh = blockIdx.x;
  int q0 = blockIdx.y * 128 + w * 32;
  const _Float16* Qp = Qb + bh * (Ss * DK);
  const _Float16* Kp = Kb + bh * (Ss * DK);
  const _Float16* Vp = Vt + bh * (DK * Ss);

  // staging: lane l -> row base+(l>>3), LDS slot l&7; global slot = (l&7)^(row&7)
  int srow = l >> 3;
  int sslot = (l & 7) ^ (srow & 7);
  int w16 = w * 16;
  const _Float16* ksrc0 = Kp + (w16 + srow) * DK + sslot * 8;
  const _Float16* ksrc1 = Kp + (w16 + 8 + srow) * DK + sslot * 8;
  const _Float16* vsrc0 = Vp + (w16 + srow) * Ss + sslot * 8;
  const _Float16* vsrc1 = Vp + (w16 + 8 + srow) * Ss + sslot * 8;

#define STAGE(KV0, BUF)                                                   \
  {                                                                       \
    gload16(ksrc0 + (KV0) * DK, &Kl[BUF][w16 * 64]);                      \
    gload16(ksrc1 + (KV0) * DK, &Kl[BUF][(w16 + 8) * 64]);                \
    gload16(vsrc0 + (KV0), &Vl[BUF][w16 * 64]);                           \
    gload16(vsrc1 + (KV0), &Vl[BUF][(w16 + 8) * 64]);                     \
  }

  // Q as B-operand: col=q=q0+l31, k=dk=s*16+hi*8+i
  f16x8 qf[4];
#pragma unroll
  for (int s = 0; s < 4; s++)
    qf[s] = *(const f16x8*)(Qp + (q0 + l31) * DK + s * 16 + hi * 8);

  f32x16 o0 = {}, o1 = {};    // ctx^T: row d=dg*32+(r&3)+8*(r>>2)+4*hi, col q=l31
  float mrun = -1e30f, lrun = 0.f;   // lrun is LANE-PARTIAL (this half's sum)

  // swizzled LDS read slots: slot = ((s*2+hi) ^ (row&7)), row&7 == l31&7 for our reads
  int kv7 = l31 & 7;
  int rslot[4];
#pragma unroll
  for (int s = 0; s < 4; s++) rslot[s] = ((s * 2 + hi) ^ kv7) * 8;

  STAGE(0, 0)
  __syncthreads();

  int cur = 0;
  for (int kv0 = 0; kv0 < Ss; kv0 += KVT) {
    // issue next-tile staging (DMA completes under this tile's compute)
    if (kv0 + KVT < Ss) STAGE(kv0 + KVT, cur ^ 1)

    // ---- QK^T (swapped): A=K rows kv from LDS, B=qf ----
    const _Float16* Kc = &Kl[cur][0];
    f32x16 s0 = {}, s1 = {};
#pragma unroll
    for (int s = 0; s < 4; s++) {
      f16x8 ka = *(const f16x8*)&Kc[l31 * 64 + rslot[s]];
      s0 = __builtin_amdgcn_mfma_f32_32x32x16_f16(ka, qf[s], s0, 0, 0, 0);
    }
#pragma unroll
    for (int s = 0; s < 4; s++) {
      f16x8 kb = *(const f16x8*)&Kc[(32 + l31) * 64 + rslot[s]];
      s1 = __builtin_amdgcn_mfma_f32_32x32x16_f16(kb, qf[s], s1, 0, 0, 0);
    }

    // ---- lane-local online softmax (exp2 domain, 1 v_exp per P) ----
    float m8[8];
#pragma unroll
    for (int r = 0; r < 8; r++)
      m8[r] = fmaxf(fmaxf(s0[r], s0[r + 8]), fmaxf(s1[r], s1[r + 8]));  // v_max3-fusable
#pragma unroll
    for (int d = 4; d >= 1; d >>= 1)
#pragma unroll
      for (int r = 0; r < 4; r++) if (r < d) m8[r] = fmaxf(m8[r], m8[r + d]);
    float pm = xhalf_max(m8[0]);

    if (!__all(pm - mrun <= 8.f)) {        // defer-max (T13), log2 units: P <= 2^8
      float mn = fmaxf(mrun, pm);
      float sc_ = ex2(mrun - mn);
      mrun = mn;
      lrun *= sc_;
#pragma unroll
      for (int r = 0; r < 16; r++) { o0[r] *= sc_; o1[r] *= sc_; }
    }
#pragma unroll
    for (int r = 0; r < 16; r++) {
      s0[r] = ex2(s0[r] - mrun);
      s1[r] = ex2(s1[r] - mrun);
    }
    float s8[8];
#pragma unroll
    for (int r = 0; r < 8; r++) s8[r] = (s0[r] + s0[r + 8]) + (s1[r] + s1[r + 8]);
#pragma unroll
    for (int d = 4; d >= 1; d >>= 1)
#pragma unroll
      for (int r = 0; r < 4; r++) if (r < d) s8[r] += s8[r + d];
    lrun += s8[0];    // lane-partial; cross-half reduce deferred to epilogue

    // ---- pack P + permlane32_swap + PV MFMA (V from LDS, swizzled) ----
    const _Float16* Vc = &Vl[cur][0];
#define PVSTEP(SRC, OFF, KST)                                                   \
    {                                                                           \
      unsigned a0 = pk2u(SRC[(OFF) + 0], SRC[(OFF) + 1]);                       \
      unsigned a1 = pk2u(SRC[(OFF) + 2], SRC[(OFF) + 3]);                       \
      unsigned b0 = pk2u(SRC[(OFF) + 4], SRC[(OFF) + 5]);                       \
      unsigned b1 = pk2u(SRC[(OFF) + 6], SRC[(OFF) + 7]);                       \
      uint2v r0 = __builtin_amdgcn_permlane32_swap(a0, b0, false, false);       \
      uint2v r1 = __builtin_amdgcn_permlane32_swap(a1, b1, false, false);       \
      union { unsigned u[4]; f16x8 v; } pf;                                     \
      pf.u[0] = r0[0]; pf.u[1] = r1[0]; pf.u[2] = r0[1]; pf.u[3] = r1[1];       \
      f16x8 v0 = *(const f16x8*)&Vc[l31 * 64 + rslot[KST]];                     \
      f16x8 v1 = *(const f16x8*)&Vc[(32 + l31) * 64 + rslot[KST]];              \
      o0 = __builtin_amdgcn_mfma_f32_32x32x16_f16(v0, pf.v, o0, 0, 0, 0);       \
      o1 = __builtin_amdgcn_mfma_f32_32x32x16_f16(v1, pf.v, o1, 0, 0, 0);       \
    }
    PVSTEP(s0, 0, 0)
    PVSTEP(s0, 8, 1)
    PVSTEP(s1, 0, 2)
    PVSTEP(s1, 8, 3)
#undef PVSTEP

    __syncthreads();   // reads of buf[cur] done; staging of buf[cur^1] drained
    cur ^= 1;
  }

  // ---- epilogue: reduce lane-partial lrun, normalize, add residual ----
  lrun += __shfl_xor(lrun, 32);
  int b = bh >> 4, h = bh & 15;
  float inv = 1.f / lrun;
  int base = (b * Ss + q0 + l31) * Dd + h * 64;
#pragma unroll
  for (int rq = 0; rq < 4; rq++) {
    int d0 = rq * 8 + hi * 4;
    float4 qv0 = *(const float4*)(query + base + d0);
    float4 ov0;
    ov0.x = o0[rq * 4 + 0] * inv + qv0.x;
    ov0.y = o0[rq * 4 + 1] * inv + qv0.y;
    ov0.z = o0[rq * 4 + 2] * inv + qv0.z;
    ov0.w = o0[rq * 4 + 3] * inv + qv0.w;
    *(float4*)(outp + base + d0) = ov0;
    float4 qv1 = *(const float4*)(query + base + 32 + d0);
    float4 ov1;
    ov1.x = o1[rq * 4 + 0] * inv + qv1.x;
    ov1.y = o1[rq * 4 + 1] * inv + qv1.y;
    ov1.z = o1[rq * 4 + 2] * inv + qv1.z;
    ov1.w = o1[rq * 4 + 3] * inv + qv1.w;
    *(float4*)(outp + base + 32 + d0) = ov1;
  }
#undef STAGE
}

extern "C" void kernel_launch(void* const* d_in, const int* in_sizes, int n_in,
                              void* d_out, int out_size, void* d_ws, size_t ws_size,
                              hipStream_t stream) {
  const float* query = (const float*)d_in[0];
  const float* key   = (const float*)d_in[1];
  const float* value = (const float*)d_in[2];
  const float* Wq = (const float*)d_in[3];
  const float* bq = (const float*)d_in[4];
  const float* Wk = (const float*)d_in[5];
  const float* bk = (const float*)d_in[6];
  const float* Wv = (const float*)d_in[7];
  const float* bv = (const float*)d_in[8];
  float* out = (float*)d_out;

  _Float16* ws = (_Float16*)d_ws;
  const size_t ACT = (size_t)Mm * Dd;
  const size_t WSZ = (size_t)Dd * Dd;
  _Float16* Xq   = ws;
  _Float16* Xk   = Xq + ACT;
  _Float16* Xv   = Xk + ACT;
  _Float16* Wtq  = Xv + ACT;
  _Float16* Wtk  = Wtq + WSZ;
  _Float16* Wtv  = Wtk + WSZ;
  _Float16* Qb   = Wtv + WSZ;
  _Float16* Kb   = Qb + ACT;
  _Float16* VtT  = Kb + ACT;   // gemm writes V^T [bh][dk][s] here directly

  cvt_act<<<dim3(4096, 1, 3), dim3(256), 0, stream>>>(query, key, value, Xq, Xk, Xv);
  cvt_wt<<<dim3(16, 16, 3), dim3(256), 0, stream>>>(Wq, Wk, Wv, Wtq, Wtk, Wtv);
  gemm_qkv<<<dim3(64, 8, 3), dim3(256), 0, stream>>>(Xq, Xk, Xv, Wtq, Wtk, Wtv,
                                                     bq, bk, bv, Qb, Kb, VtT);
  attn<<<dim3(64, 16), dim3(256), 0, stream>>>(Qb, Kb, VtT, query, out);
}

// Round 17
// 211.313 us; speedup vs baseline: 1.1941x; 1.0423x over previous
//
#include <hip/hip_runtime.h>
#include <hip/hip_bf16.h>
#include <stdint.h>

#define Bb 4
#define Ss 2048
#define Dd 1024
#define Hh 16
#define DK 64
#define BH 64
#define Mm 8192
#define KVT 64

typedef __attribute__((ext_vector_type(8))) _Float16 f16x8;
typedef __attribute__((ext_vector_type(4))) _Float16 f16x4;
typedef __attribute__((ext_vector_type(2))) __fp16 fp16x2;
typedef __attribute__((ext_vector_type(4))) float f32x4;
typedef __attribute__((ext_vector_type(16))) float f32x16;
typedef __attribute__((ext_vector_type(2))) unsigned uint2v;

__device__ __forceinline__ void gload16(const _Float16* g, _Float16* lds) {
  __builtin_amdgcn_global_load_lds((const __attribute__((address_space(1))) unsigned int*)g,
                                   (__attribute__((address_space(3))) unsigned int*)lds, 16, 0, 0);
}

// single v_exp_f32 (2^x). exp2f() is the libm path — the r11 regression.
#if __has_builtin(__builtin_amdgcn_exp2f)
__device__ __forceinline__ float ex2(float x) { return __builtin_amdgcn_exp2f(x); }
#else
__device__ __forceinline__ float ex2(float x) {
  float r; asm("v_exp_f32 %0, %1" : "=v"(r) : "v"(x)); return r;
}
#endif

// pack two f32 -> u32 of 2 f16 (v_cvt_pkrtz_f16_f32, 1 inst)
__device__ __forceinline__ unsigned pk2u(float a, float b) {
  union { fp16x2 h; unsigned u; } x;
  x.h = __builtin_amdgcn_cvt_pkrtz(a, b);
  return x.u;
}

// cross-half (lane ^ 32) max via permlane32_swap (VALU, not ds_bpermute)
__device__ __forceinline__ float xhalf_max(float x) {
  union { float f; unsigned u; } a; a.f = x;
  uint2v r = __builtin_amdgcn_permlane32_swap(a.u, a.u, false, false);
  union { unsigned u; float f; } b0, b1; b0.u = r[0]; b1.u = r[1];
  return fmaxf(fmaxf(x, b0.f), b1.f);
}

// ---------------- K0a: convert activations fp32 -> fp16 ----------------
__global__ __launch_bounds__(256) void cvt_act(const float* __restrict__ q,
                                               const float* __restrict__ k,
                                               const float* __restrict__ v,
                                               _Float16* __restrict__ xq,
                                               _Float16* __restrict__ xk,
                                               _Float16* __restrict__ xv) {
  const float* src = blockIdx.z == 0 ? q : (blockIdx.z == 1 ? k : v);
  _Float16* dst = blockIdx.z == 0 ? xq : (blockIdx.z == 1 ? xk : xv);
  int i = (blockIdx.x * 256 + threadIdx.x) * 8;
  float4 a = *(const float4*)(src + i);
  float4 b = *(const float4*)(src + i + 4);
  union { f16x8 v8; _Float16 h[8]; } o;
  o.h[0] = (_Float16)a.x; o.h[1] = (_Float16)a.y; o.h[2] = (_Float16)a.z; o.h[3] = (_Float16)a.w;
  o.h[4] = (_Float16)b.x; o.h[5] = (_Float16)b.y; o.h[6] = (_Float16)b.z; o.h[7] = (_Float16)b.w;
  *(f16x8*)(dst + i) = o.v8;
}

// ---------------- K0b: convert + transpose weights: Wt[n][k] = f16(W[k][n]) ----------------
// Q weights pre-scaled by log2(e): attention scores land in the exp2 domain.
__global__ __launch_bounds__(256) void cvt_wt(const float* __restrict__ wq,
                                              const float* __restrict__ wk,
                                              const float* __restrict__ wv,
                                              _Float16* __restrict__ tq,
                                              _Float16* __restrict__ tk,
                                              _Float16* __restrict__ tv) {
  const float* w = blockIdx.z == 0 ? wq : (blockIdx.z == 1 ? wk : wv);
  _Float16* o = blockIdx.z == 0 ? tq : (blockIdx.z == 1 ? tk : tv);
  float wscale = blockIdx.z == 0 ? 1.4426950408889634f : 1.0f;
  __shared__ float tile[64][65];
  int k0 = blockIdx.x * 64;
  int n0 = blockIdx.y * 64;
  int t = threadIdx.x;
  int tr = t >> 4;
  int tc = (t & 15) * 4;
  for (int i = 0; i < 4; i++) {
    int r = i * 16 + tr;
    float4 val = *(const float4*)(w + (k0 + r) * Dd + n0 + tc);
    tile[r][tc + 0] = val.x; tile[r][tc + 1] = val.y;
    tile[r][tc + 2] = val.z; tile[r][tc + 3] = val.w;
  }
  __syncthreads();
  for (int i = 0; i < 2; i++) {
    int vdx = t + 256 * i;
    int rn = vdx >> 3;
    int c8 = (vdx & 7) * 8;
    union { f16x8 v8; _Float16 h[8]; } o2;
    for (int j = 0; j < 8; j++) o2.h[j] = (_Float16)(tile[c8 + j][rn] * wscale);
    *(f16x8*)(o + (n0 + rn) * Dd + k0 + c8) = o2.v8;
  }
}

// ---------------- K1: projection GEMM (m97 structure) ----------------
// Q,K outputs in [bh][s][dk]; V output written TRANSPOSED [bh][dk][s].
__global__ __launch_bounds__(256) void gemm_qkv(
    const _Float16* __restrict__ xq, const _Float16* __restrict__ xk,
    const _Float16* __restrict__ xv,
    const _Float16* __restrict__ wtq, const _Float16* __restrict__ wtk,
    const _Float16* __restrict__ wtv,
    const float* __restrict__ bq, const float* __restrict__ bk, const float* __restrict__ bv,
    _Float16* __restrict__ oq, _Float16* __restrict__ ok,
    _Float16* __restrict__ ov) {
  int z = blockIdx.z;
  const _Float16* A  = z == 0 ? xq  : (z == 1 ? xk  : xv);
  const _Float16* Bt = z == 0 ? wtq : (z == 1 ? wtk : wtv);
  const float* bias  = z == 0 ? bq  : (z == 1 ? bk  : bv);
  _Float16* out      = z == 0 ? oq  : (z == 1 ? ok  : ov);
  float bscale       = z == 0 ? 1.4426950408889634f : 1.0f;

  __shared__ _Float16 As[128 * 64];
  __shared__ _Float16 Bs[128 * 64];

  int tid = threadIdx.x;
  int w = tid >> 6;
  int l = tid & 63;
  int lr = l & 15, lk = l >> 4;
  int m0 = blockIdx.x * 128;
  int n0 = blockIdx.y * 128;
  int wr = (w >> 1) * 64;
  int wc = (w & 1) * 64;

  f32x4 acc[4][4] = {};

  for (int kt = 0; kt < Dd; kt += 64) {
    __syncthreads();
    for (int i = 0; i < 4; i++) {
      int fbase = i * 256 + w * 64;     // wave-uniform chunk base
      int f = fbase + l;
      int r = f >> 3, c = (f & 7) * 8;
      gload16(A + (m0 + r) * Dd + kt + c, &As[fbase * 8]);
      gload16(Bt + (n0 + r) * Dd + kt + c, &Bs[fbase * 8]);
    }
    __syncthreads();
    for (int kh = 0; kh < 2; kh++) {
      f16x8 af[4], bfr[4];
      for (int mi = 0; mi < 4; mi++)
        af[mi] = *(const f16x8*)&As[(wr + mi * 16 + lr) * 64 + kh * 32 + lk * 8];
      for (int ni = 0; ni < 4; ni++)
        bfr[ni] = *(const f16x8*)&Bs[(wc + ni * 16 + lr) * 64 + kh * 32 + lk * 8];
      for (int mi = 0; mi < 4; mi++)
        for (int ni = 0; ni < 4; ni++)
          acc[mi][ni] = __builtin_amdgcn_mfma_f32_16x16x32_f16(af[mi], bfr[ni], acc[mi][ni], 0, 0, 0);
    }
  }

  if (z == 2) {
    // V^T epilogue: lane holds 4 consecutive s for fixed dk -> one aligned 8B store
    for (int mi = 0; mi < 4; mi++) {
      for (int ni = 0; ni < 4; ni++) {
        int n = n0 + wc + ni * 16 + lr;
        float bval = bias[n];
        int h = n >> 6, dk = n & 63;
        int m = m0 + wr + mi * 16 + lk * 4;
        int b = m >> 11, s = m & 2047;
        f16x4 o4;
        for (int j = 0; j < 4; j++) o4[j] = (_Float16)(acc[mi][ni][j] + bval);
        *(f16x4*)(out + ((size_t)((b * Hh + h) * DK + dk) * Ss + s)) = o4;
      }
    }
  } else {
    for (int mi = 0; mi < 4; mi++) {
      for (int ni = 0; ni < 4; ni++) {
        int n = n0 + wc + ni * 16 + lr;
        float bval = bias[n] * bscale;
        int h = n >> 6, dk = n & 63;
        for (int j = 0; j < 4; j++) {
          int m = m0 + wr + mi * 16 + lk * 4 + j;
          int b = m >> 11, s = m & 2047;
          out[((b * Hh + h) * Ss + s) * DK + dk] = (_Float16)(acc[mi][ni][j] + bval);
        }
      }
    }
  }
}

// ---------------- K3: flash attention, 32x32x16, LDS dbuf K/V, kv-loop unrolled x2 ----------------
// Identical math/barrier structure to r16 (135.6us). VALU-diet changes only:
// (a) kv loop unrolled x2 -> Kl[0]/Kl[1]/Vl[0]/Vl[1] are COMPILE-TIME bases: per-tile LDS
//     read addresses become one loop-invariant vaddr + offset: immediates (zero per-tile math);
// (b) stage global pointers strength-reduced to running += increments (no per-tile 64-bit
//     base+KV0*stride rebuilds).
__global__ __launch_bounds__(256) void attn(const _Float16* __restrict__ Qb,
                                            const _Float16* __restrict__ Kb,
                                            const _Float16* __restrict__ Vt,
                                            const float* __restrict__ query,
                                            float* __restrict__ outp) {
  __shared__ _Float16 Kl[2][KVT * 64];
  __shared__ _Float16 Vl[2][KVT * 64];

  int tid = threadIdx.x;
  int w = tid >> 6, l = tid & 63;
  int l31 = l & 31, hi = l >> 5;
  int bh = blockIdx.x;
  int q0 = blockIdx.y * 128 + w * 32;
  const _Float16* Qp = Qb + bh * (Ss * DK);
  const _Float16* Kp = Kb + bh * (Ss * DK);
  const _Float16* Vp = Vt + bh * (DK * Ss);

  // staging: lane l -> row base+(l>>3), LDS slot l&7; global slot = (l&7)^(row&7)
  int srow = l >> 3;
  int sslot = (l & 7) ^ (srow & 7);
  int w16 = w * 16;
  // running stage pointers (strength-reduced; advanced after each STAGE)
  const _Float16* kp0 = Kp + (w16 + srow) * DK + sslot * 8;
  const _Float16* kp1 = Kp + (w16 + 8 + srow) * DK + sslot * 8;
  const _Float16* vp0 = Vp + (w16 + srow) * Ss + sslot * 8;
  const _Float16* vp1 = Vp + (w16 + 8 + srow) * Ss + sslot * 8;

#define STAGE(BUF)                                                        \
  {                                                                       \
    gload16(kp0, &Kl[BUF][w16 * 64]);                                     \
    gload16(kp1, &Kl[BUF][(w16 + 8) * 64]);                               \
    gload16(vp0, &Vl[BUF][w16 * 64]);                                     \
    gload16(vp1, &Vl[BUF][(w16 + 8) * 64]);                               \
    kp0 += KVT * DK; kp1 += KVT * DK; vp0 += KVT; vp1 += KVT;             \
  }

  // Q as B-operand: col=q=q0+l31, k=dk=s*16+hi*8+i
  f16x8 qf[4];
#pragma unroll
  for (int s = 0; s < 4; s++)
    qf[s] = *(const f16x8*)(Qp + (q0 + l31) * DK + s * 16 + hi * 8);

  f32x16 o0 = {}, o1 = {};    // ctx^T: row d=dg*32+(r&3)+8*(r>>2)+4*hi, col q=l31
  float mrun = -1e30f, lrun = 0.f;   // lrun is LANE-PARTIAL (this half's sum)

  // swizzled LDS read slots: slot = ((s*2+hi) ^ (row&7)), row&7 == l31&7 for our reads
  int kv7 = l31 & 7;
  int rslot[4];
#pragma unroll
  for (int s = 0; s < 4; s++) rslot[s] = ((s * 2 + hi) ^ kv7) * 8;

  // TILE: full per-tile compute on compile-time buffer BUF
#define TILE(BUF)                                                               \
  {                                                                             \
    f32x16 s0 = {}, s1 = {};                                                    \
    _Pragma("unroll")                                                           \
    for (int s = 0; s < 4; s++) {                                               \
      f16x8 ka = *(const f16x8*)&Kl[BUF][l31 * 64 + rslot[s]];                  \
      s0 = __builtin_amdgcn_mfma_f32_32x32x16_f16(ka, qf[s], s0, 0, 0, 0);      \
    }                                                                           \
    _Pragma("unroll")                                                           \
    for (int s = 0; s < 4; s++) {                                               \
      f16x8 kb = *(const f16x8*)&Kl[BUF][(32 + l31) * 64 + rslot[s]];           \
      s1 = __builtin_amdgcn_mfma_f32_32x32x16_f16(kb, qf[s], s1, 0, 0, 0);      \
    }                                                                           \
    float m8[8];                                                                \
    _Pragma("unroll")                                                           \
    for (int r = 0; r < 8; r++)                                                 \
      m8[r] = fmaxf(fmaxf(s0[r], s0[r + 8]), fmaxf(s1[r], s1[r + 8]));          \
    _Pragma("unroll")                                                           \
    for (int d = 4; d >= 1; d >>= 1)                                            \
      for (int r = 0; r < 4; r++) if (r < d) m8[r] = fmaxf(m8[r], m8[r + d]);   \
    float pm = xhalf_max(m8[0]);                                                \
    if (!__all(pm - mrun <= 8.f)) {   /* defer-max (T13), log2 units */         \
      float mn = fmaxf(mrun, pm);                                               \
      float sc_ = ex2(mrun - mn);                                               \
      mrun = mn;                                                                \
      lrun *= sc_;                                                              \
      _Pragma("unroll")                                                         \
      for (int r = 0; r < 16; r++) { o0[r] *= sc_; o1[r] *= sc_; }              \
    }                                                                           \
    _Pragma("unroll")                                                           \
    for (int r = 0; r < 16; r++) {                                              \
      s0[r] = ex2(s0[r] - mrun);                                                \
      s1[r] = ex2(s1[r] - mrun);                                                \
    }                                                                           \
    float s8[8];                                                                \
    _Pragma("unroll")                                                           \
    for (int r = 0; r < 8; r++) s8[r] = (s0[r] + s0[r + 8]) + (s1[r] + s1[r + 8]); \
    _Pragma("unroll")                                                           \
    for (int d = 4; d >= 1; d >>= 1)                                            \
      for (int r = 0; r < 4; r++) if (r < d) s8[r] += s8[r + d];                \
    lrun += s8[0];                                                              \
    PVSTEP(BUF, s0, 0, 0)                                                       \
    PVSTEP(BUF, s0, 8, 1)                                                       \
    PVSTEP(BUF, s1, 0, 2)                                                       \
    PVSTEP(BUF, s1, 8, 3)                                                       \
  }

#define PVSTEP(BUF, SRC, OFF, KST)                                              \
    {                                                                           \
      unsigned a0 = pk2u(SRC[(OFF) + 0], SRC[(OFF) + 1]);                       \
      unsigned a1 = pk2u(SRC[(OFF) + 2], SRC[(OFF) + 3]);                       \
      unsigned b0 = pk2u(SRC[(OFF) + 4], SRC[(OFF) + 5]);                       \
      unsigned b1 = pk2u(SRC[(OFF) + 6], SRC[(OFF) + 7]);                       \
      uint2v r0 = __builtin_amdgcn_permlane32_swap(a0, b0, false, false);       \
      uint2v r1 = __builtin_amdgcn_permlane32_swap(a1, b1, false, false);       \
      union { unsigned u[4]; f16x8 v; } pf;                                     \
      pf.u[0] = r0[0]; pf.u[1] = r1[0]; pf.u[2] = r0[1]; pf.u[3] = r1[1];       \
      f16x8 v0 = *(const f16x8*)&Vl[BUF][l31 * 64 + rslot[KST]];                \
      f16x8 v1 = *(const f16x8*)&Vl[BUF][(32 + l31) * 64 + rslot[KST]];         \
      o0 = __builtin_amdgcn_mfma_f32_32x32x16_f16(v0, pf.v, o0, 0, 0, 0);       \
      o1 = __builtin_amdgcn_mfma_f32_32x32x16_f16(v1, pf.v, o1, 0, 0, 0);       \
    }

  STAGE(0)
  __syncthreads();

  // 15 double-tiles with full prefetch, then the final pair (no stage past end)
  for (int it = 0; it < 15; ++it) {
    STAGE(1)
    TILE(0)
    __syncthreads();
    STAGE(0)
    TILE(1)
    __syncthreads();
  }
  STAGE(1)
  TILE(0)
  __syncthreads();
  TILE(1)
#undef PVSTEP
#undef TILE
#undef STAGE

  // ---- epilogue: reduce lane-partial lrun, normalize, add residual ----
  lrun += __shfl_xor(lrun, 32);
  int b = bh >> 4, h = bh & 15;
  float inv = 1.f / lrun;
  int base = (b * Ss + q0 + l31) * Dd + h * 64;
#pragma unroll
  for (int rq = 0; rq < 4; rq++) {
    int d0 = rq * 8 + hi * 4;
    float4 qv0 = *(const float4*)(query + base + d0);
    float4 ov0;
    ov0.x = o0[rq * 4 + 0] * inv + qv0.x;
    ov0.y = o0[rq * 4 + 1] * inv + qv0.y;
    ov0.z = o0[rq * 4 + 2] * inv + qv0.z;
    ov0.w = o0[rq * 4 + 3] * inv + qv0.w;
    *(float4*)(outp + base + d0) = ov0;
    float4 qv1 = *(const float4*)(query + base + 32 + d0);
    float4 ov1;
    ov1.x = o1[rq * 4 + 0] * inv + qv1.x;
    ov1.y = o1[rq * 4 + 1] * inv + qv1.y;
    ov1.z = o1[rq * 4 + 2] * inv + qv1.z;
    ov1.w = o1[rq * 4 + 3] * inv + qv1.w;
    *(float4*)(outp + base + 32 + d0) = ov1;
  }
}

extern "C" void kernel_launch(void* const* d_in, const int* in_sizes, int n_in,
                              void* d_out, int out_size, void* d_ws, size_t ws_size,
                              hipStream_t stream) {
  const float* query = (const float*)d_in[0];
  const float* key   = (const float*)d_in[1];
  const float* value = (const float*)d_in[2];
  const float* Wq = (const float*)d_in[3];
  const float* bq = (const float*)d_in[4];
  const float* Wk = (const float*)d_in[5];
  const float* bk = (const float*)d_in[6];
  const float* Wv = (const float*)d_in[7];
  const float* bv = (const float*)d_in[8];
  float* out = (float*)d_out;

  _Float16* ws = (_Float16*)d_ws;
  const size_t ACT = (size_t)Mm * Dd;
  const size_t WSZ = (size_t)Dd * Dd;
  _Float16* Xq   = ws;
  _Float16* Xk   = Xq + ACT;
  _Float16* Xv   = Xk + ACT;
  _Float16* Wtq  = Xv + ACT;
  _Float16* Wtk  = Wtq + WSZ;
  _Float16* Wtv  = Wtk + WSZ;
  _Float16* Qb   = Wtv + WSZ;
  _Float16* Kb   = Qb + ACT;
  _Float16* VtT  = Kb + ACT;   // gemm writes V^T [bh][dk][s] here directly

  cvt_act<<<dim3(4096, 1, 3), dim3(256), 0, stream>>>(query, key, value, Xq, Xk, Xv);
  cvt_wt<<<dim3(16, 16, 3), dim3(256), 0, stream>>>(Wq, Wk, Wv, Wtq, Wtk, Wtv);
  gemm_qkv<<<dim3(64, 8, 3), dim3(256), 0, stream>>>(Xq, Xk, Xv, Wtq, Wtk, Wtv,
                                                     bq, bk, bv, Qb, Kb, VtT);
  attn<<<dim3(64, 16), dim3(256), 0, stream>>>(Qb, Kb, VtT, query, out);
}

// Round 18
// 203.226 us; speedup vs baseline: 1.2416x; 1.0398x over previous
//
#include <hip/hip_runtime.h>
#include <hip/hip_bf16.h>
#include <stdint.h>

#define Bb 4
#define Ss 2048
#define Dd 1024
#define Hh 16
#define DK 64
#define BH 64
#define Mm 8192
#define KVT 64

typedef __attribute__((ext_vector_type(8))) _Float16 f16x8;
typedef __attribute__((ext_vector_type(4))) _Float16 f16x4;
typedef __attribute__((ext_vector_type(2))) __fp16 fp16x2;
typedef __attribute__((ext_vector_type(4))) float f32x4;
typedef __attribute__((ext_vector_type(16))) float f32x16;
typedef __attribute__((ext_vector_type(2))) unsigned uint2v;

__device__ __forceinline__ void gload16(const _Float16* g, _Float16* lds) {
  __builtin_amdgcn_global_load_lds((const __attribute__((address_space(1))) unsigned int*)g,
                                   (__attribute__((address_space(3))) unsigned int*)lds, 16, 0, 0);
}

// single v_exp_f32 (2^x). exp2f() is the libm path — the r11 regression.
#if __has_builtin(__builtin_amdgcn_exp2f)
__device__ __forceinline__ float ex2(float x) { return __builtin_amdgcn_exp2f(x); }
#else
__device__ __forceinline__ float ex2(float x) {
  float r; asm("v_exp_f32 %0, %1" : "=v"(r) : "v"(x)); return r;
}
#endif

// pack two f32 -> u32 of 2 f16 (v_cvt_pkrtz_f16_f32, 1 inst)
__device__ __forceinline__ unsigned pk2u(float a, float b) {
  union { fp16x2 h; unsigned u; } x;
  x.h = __builtin_amdgcn_cvt_pkrtz(a, b);
  return x.u;
}

// cross-half (lane ^ 32) max via permlane32_swap (VALU, not ds_bpermute)
__device__ __forceinline__ float xhalf_max(float x) {
  union { float f; unsigned u; } a; a.f = x;
  uint2v r = __builtin_amdgcn_permlane32_swap(a.u, a.u, false, false);
  union { unsigned u; float f; } b0, b1; b0.u = r[0]; b1.u = r[1];
  return fmaxf(fmaxf(x, b0.f), b1.f);
}

// ---------------- K0b: convert + transpose weights: Wt[n][k] = f16(W[k][n]) ----------------
// Q weights pre-scaled by log2(e): attention scores land in the exp2 domain.
__global__ __launch_bounds__(256) void cvt_wt(const float* __restrict__ wq,
                                              const float* __restrict__ wk,
                                              const float* __restrict__ wv,
                                              _Float16* __restrict__ tq,
                                              _Float16* __restrict__ tk,
                                              _Float16* __restrict__ tv) {
  const float* w = blockIdx.z == 0 ? wq : (blockIdx.z == 1 ? wk : wv);
  _Float16* o = blockIdx.z == 0 ? tq : (blockIdx.z == 1 ? tk : tv);
  float wscale = blockIdx.z == 0 ? 1.4426950408889634f : 1.0f;
  __shared__ float tile[64][65];
  int k0 = blockIdx.x * 64;
  int n0 = blockIdx.y * 64;
  int t = threadIdx.x;
  int tr = t >> 4;
  int tc = (t & 15) * 4;
  for (int i = 0; i < 4; i++) {
    int r = i * 16 + tr;
    float4 val = *(const float4*)(w + (k0 + r) * Dd + n0 + tc);
    tile[r][tc + 0] = val.x; tile[r][tc + 1] = val.y;
    tile[r][tc + 2] = val.z; tile[r][tc + 3] = val.w;
  }
  __syncthreads();
  for (int i = 0; i < 2; i++) {
    int vdx = t + 256 * i;
    int rn = vdx >> 3;
    int c8 = (vdx & 7) * 8;
    union { f16x8 v8; _Float16 h[8]; } o2;
    for (int j = 0; j < 8; j++) o2.h[j] = (_Float16)(tile[c8 + j][rn] * wscale);
    *(f16x8*)(o + (n0 + rn) * Dd + k0 + c8) = o2.v8;
  }
}

// ---------------- K1: projection GEMM (m97 structure, fp32-A fused conversion) ----------------
// A is the RAW fp32 activation (query/key/value): staged to f16 LDS via in-register
// cvt_pkrtz (short-range load->cvt->ds_write inside one barrier phase — NOT cross-tile
// reg-pipelining). B (weights^T, f16) stays on global_load_lds DMA. Replaces cvt_act.
// Q,K outputs in [bh][s][dk]; V output written TRANSPOSED [bh][dk][s].
__global__ __launch_bounds__(256) void gemm_qkv(
    const float* __restrict__ aq, const float* __restrict__ ak,
    const float* __restrict__ av,
    const _Float16* __restrict__ wtq, const _Float16* __restrict__ wtk,
    const _Float16* __restrict__ wtv,
    const float* __restrict__ bq, const float* __restrict__ bk, const float* __restrict__ bv,
    _Float16* __restrict__ oq, _Float16* __restrict__ ok,
    _Float16* __restrict__ ov) {
  int z = blockIdx.z;
  const float* Af    = z == 0 ? aq  : (z == 1 ? ak  : av);
  const _Float16* Bt = z == 0 ? wtq : (z == 1 ? wtk : wtv);
  const float* bias  = z == 0 ? bq  : (z == 1 ? bk  : bv);
  _Float16* out      = z == 0 ? oq  : (z == 1 ? ok  : ov);
  float bscale       = z == 0 ? 1.4426950408889634f : 1.0f;

  __shared__ _Float16 As[128 * 64];
  __shared__ _Float16 Bs[128 * 64];

  int tid = threadIdx.x;
  int w = tid >> 6;
  int l = tid & 63;
  int lr = l & 15, lk = l >> 4;
  int m0 = blockIdx.x * 128;
  int n0 = blockIdx.y * 128;
  int wr = (w >> 1) * 64;
  int wc = (w & 1) * 64;

  f32x4 acc[4][4] = {};

  for (int kt = 0; kt < Dd; kt += 64) {
    __syncthreads();
    for (int i = 0; i < 4; i++) {
      int fbase = i * 256 + w * 64;     // wave-uniform chunk base
      int f = fbase + l;
      int r = f >> 3, c = (f & 7) * 8;
      // B: DMA (f16 weights)
      gload16(Bt + (n0 + r) * Dd + kt + c, &Bs[fbase * 8]);
      // A: fp32 load -> RTZ pack -> f16 LDS (same slot the DMA would fill)
      const float* ap = Af + (size_t)(m0 + r) * Dd + kt + c;
      float4 a0 = *(const float4*)ap;
      float4 a1 = *(const float4*)(ap + 4);
      union { unsigned u[4]; f16x8 v; } aw;
      aw.u[0] = pk2u(a0.x, a0.y); aw.u[1] = pk2u(a0.z, a0.w);
      aw.u[2] = pk2u(a1.x, a1.y); aw.u[3] = pk2u(a1.z, a1.w);
      *(f16x8*)&As[f * 8] = aw.v;
    }
    __syncthreads();
    for (int kh = 0; kh < 2; kh++) {
      f16x8 af[4], bfr[4];
      for (int mi = 0; mi < 4; mi++)
        af[mi] = *(const f16x8*)&As[(wr + mi * 16 + lr) * 64 + kh * 32 + lk * 8];
      for (int ni = 0; ni < 4; ni++)
        bfr[ni] = *(const f16x8*)&Bs[(wc + ni * 16 + lr) * 64 + kh * 32 + lk * 8];
      for (int mi = 0; mi < 4; mi++)
        for (int ni = 0; ni < 4; ni++)
          acc[mi][ni] = __builtin_amdgcn_mfma_f32_16x16x32_f16(af[mi], bfr[ni], acc[mi][ni], 0, 0, 0);
    }
  }

  if (z == 2) {
    // V^T epilogue: lane holds 4 consecutive s for fixed dk -> one aligned 8B store
    for (int mi = 0; mi < 4; mi++) {
      for (int ni = 0; ni < 4; ni++) {
        int n = n0 + wc + ni * 16 + lr;
        float bval = bias[n];
        int h = n >> 6, dk = n & 63;
        int m = m0 + wr + mi * 16 + lk * 4;
        int b = m >> 11, s = m & 2047;
        f16x4 o4;
        for (int j = 0; j < 4; j++) o4[j] = (_Float16)(acc[mi][ni][j] + bval);
        *(f16x4*)(out + ((size_t)((b * Hh + h) * DK + dk) * Ss + s)) = o4;
      }
    }
  } else {
    for (int mi = 0; mi < 4; mi++) {
      for (int ni = 0; ni < 4; ni++) {
        int n = n0 + wc + ni * 16 + lr;
        float bval = bias[n] * bscale;
        int h = n >> 6, dk = n & 63;
        for (int j = 0; j < 4; j++) {
          int m = m0 + wr + mi * 16 + lk * 4 + j;
          int b = m >> 11, s = m & 2047;
          out[((b * Hh + h) * Ss + s) * DK + dk] = (_Float16)(acc[mi][ni][j] + bval);
        }
      }
    }
  }
}

// ---------------- K3: flash attention, 32x32x16, LDS dbuf K/V, kv-loop unrolled x2 (r17, 121us) ----------------
__global__ __launch_bounds__(256) void attn(const _Float16* __restrict__ Qb,
                                            const _Float16* __restrict__ Kb,
                                            const _Float16* __restrict__ Vt,
                                            const float* __restrict__ query,
                                            float* __restrict__ outp) {
  __shared__ _Float16 Kl[2][KVT * 64];
  __shared__ _Float16 Vl[2][KVT * 64];

  int tid = threadIdx.x;
  int w = tid >> 6, l = tid & 63;
  int l31 = l & 31, hi = l >> 5;
  int bh = blockIdx.x;
  int q0 = blockIdx.y * 128 + w * 32;
  const _Float16* Qp = Qb + bh * (Ss * DK);
  const _Float16* Kp = Kb + bh * (Ss * DK);
  const _Float16* Vp = Vt + bh * (DK * Ss);

  // staging: lane l -> row base+(l>>3), LDS slot l&7; global slot = (l&7)^(row&7)
  int srow = l >> 3;
  int sslot = (l & 7) ^ (srow & 7);
  int w16 = w * 16;
  // running stage pointers (strength-reduced; advanced after each STAGE)
  const _Float16* kp0 = Kp + (w16 + srow) * DK + sslot * 8;
  const _Float16* kp1 = Kp + (w16 + 8 + srow) * DK + sslot * 8;
  const _Float16* vp0 = Vp + (w16 + srow) * Ss + sslot * 8;
  const _Float16* vp1 = Vp + (w16 + 8 + srow) * Ss + sslot * 8;

#define STAGE(BUF)                                                        \
  {                                                                       \
    gload16(kp0, &Kl[BUF][w16 * 64]);                                     \
    gload16(kp1, &Kl[BUF][(w16 + 8) * 64]);                               \
    gload16(vp0, &Vl[BUF][w16 * 64]);                                     \
    gload16(vp1, &Vl[BUF][(w16 + 8) * 64]);                               \
    kp0 += KVT * DK; kp1 += KVT * DK; vp0 += KVT; vp1 += KVT;             \
  }

  // Q as B-operand: col=q=q0+l31, k=dk=s*16+hi*8+i
  f16x8 qf[4];
#pragma unroll
  for (int s = 0; s < 4; s++)
    qf[s] = *(const f16x8*)(Qp + (q0 + l31) * DK + s * 16 + hi * 8);

  f32x16 o0 = {}, o1 = {};    // ctx^T: row d=dg*32+(r&3)+8*(r>>2)+4*hi, col q=l31
  float mrun = -1e30f, lrun = 0.f;   // lrun is LANE-PARTIAL (this half's sum)

  // swizzled LDS read slots: slot = ((s*2+hi) ^ (row&7)), row&7 == l31&7 for our reads
  int kv7 = l31 & 7;
  int rslot[4];
#pragma unroll
  for (int s = 0; s < 4; s++) rslot[s] = ((s * 2 + hi) ^ kv7) * 8;

  // TILE: full per-tile compute on compile-time buffer BUF
#define TILE(BUF)                                                               \
  {                                                                             \
    f32x16 s0 = {}, s1 = {};                                                    \
    _Pragma("unroll")                                                           \
    for (int s = 0; s < 4; s++) {                                               \
      f16x8 ka = *(const f16x8*)&Kl[BUF][l31 * 64 + rslot[s]];                  \
      s0 = __builtin_amdgcn_mfma_f32_32x32x16_f16(ka, qf[s], s0, 0, 0, 0);      \
    }                                                                           \
    _Pragma("unroll")                                                           \
    for (int s = 0; s < 4; s++) {                                               \
      f16x8 kb = *(const f16x8*)&Kl[BUF][(32 + l31) * 64 + rslot[s]];           \
      s1 = __builtin_amdgcn_mfma_f32_32x32x16_f16(kb, qf[s], s1, 0, 0, 0);      \
    }                                                                           \
    float m8[8];                                                                \
    _Pragma("unroll")                                                           \
    for (int r = 0; r < 8; r++)                                                 \
      m8[r] = fmaxf(fmaxf(s0[r], s0[r + 8]), fmaxf(s1[r], s1[r + 8]));          \
    _Pragma("unroll")                                                           \
    for (int d = 4; d >= 1; d >>= 1)                                            \
      for (int r = 0; r < 4; r++) if (r < d) m8[r] = fmaxf(m8[r], m8[r + d]);   \
    float pm = xhalf_max(m8[0]);                                                \
    if (!__all(pm - mrun <= 8.f)) {   /* defer-max (T13), log2 units */         \
      float mn = fmaxf(mrun, pm);                                               \
      float sc_ = ex2(mrun - mn);                                               \
      mrun = mn;                                                                \
      lrun *= sc_;                                                              \
      _Pragma("unroll")                                                         \
      for (int r = 0; r < 16; r++) { o0[r] *= sc_; o1[r] *= sc_; }              \
    }                                                                           \
    _Pragma("unroll")                                                           \
    for (int r = 0; r < 16; r++) {                                              \
      s0[r] = ex2(s0[r] - mrun);                                                \
      s1[r] = ex2(s1[r] - mrun);                                                \
    }                                                                           \
    float s8[8];                                                                \
    _Pragma("unroll")                                                           \
    for (int r = 0; r < 8; r++) s8[r] = (s0[r] + s0[r + 8]) + (s1[r] + s1[r + 8]); \
    _Pragma("unroll")                                                           \
    for (int d = 4; d >= 1; d >>= 1)                                            \
      for (int r = 0; r < 4; r++) if (r < d) s8[r] += s8[r + d];                \
    lrun += s8[0];                                                              \
    PVSTEP(BUF, s0, 0, 0)                                                       \
    PVSTEP(BUF, s0, 8, 1)                                                       \
    PVSTEP(BUF, s1, 0, 2)                                                       \
    PVSTEP(BUF, s1, 8, 3)                                                       \
  }

#define PVSTEP(BUF, SRC, OFF, KST)                                              \
    {                                                                           \
      unsigned a0 = pk2u(SRC[(OFF) + 0], SRC[(OFF) + 1]);                       \
      unsigned a1 = pk2u(SRC[(OFF) + 2], SRC[(OFF) + 3]);                       \
      unsigned b0 = pk2u(SRC[(OFF) + 4], SRC[(OFF) + 5]);                       \
      unsigned b1 = pk2u(SRC[(OFF) + 6], SRC[(OFF) + 7]);                       \
      uint2v r0 = __builtin_amdgcn_permlane32_swap(a0, b0, false, false);       \
      uint2v r1 = __builtin_amdgcn_permlane32_swap(a1, b1, false, false);       \
      union { unsigned u[4]; f16x8 v; } pf;                                     \
      pf.u[0] = r0[0]; pf.u[1] = r1[0]; pf.u[2] = r0[1]; pf.u[3] = r1[1];       \
      f16x8 v0 = *(const f16x8*)&Vl[BUF][l31 * 64 + rslot[KST]];                \
      f16x8 v1 = *(const f16x8*)&Vl[BUF][(32 + l31) * 64 + rslot[KST]];         \
      o0 = __builtin_amdgcn_mfma_f32_32x32x16_f16(v0, pf.v, o0, 0, 0, 0);       \
      o1 = __builtin_amdgcn_mfma_f32_32x32x16_f16(v1, pf.v, o1, 0, 0, 0);       \
    }

  STAGE(0)
  __syncthreads();

  // 15 double-tiles with full prefetch, then the final pair (no stage past end)
  for (int it = 0; it < 15; ++it) {
    STAGE(1)
    TILE(0)
    __syncthreads();
    STAGE(0)
    TILE(1)
    __syncthreads();
  }
  STAGE(1)
  TILE(0)
  __syncthreads();
  TILE(1)
#undef PVSTEP
#undef TILE
#undef STAGE

  // ---- epilogue: reduce lane-partial lrun, normalize, add residual ----
  lrun += __shfl_xor(lrun, 32);
  int b = bh >> 4, h = bh & 15;
  float inv = 1.f / lrun;
  int base = (b * Ss + q0 + l31) * Dd + h * 64;
#pragma unroll
  for (int rq = 0; rq < 4; rq++) {
    int d0 = rq * 8 + hi * 4;
    float4 qv0 = *(const float4*)(query + base + d0);
    float4 ov0;
    ov0.x = o0[rq * 4 + 0] * inv + qv0.x;
    ov0.y = o0[rq * 4 + 1] * inv + qv0.y;
    ov0.z = o0[rq * 4 + 2] * inv + qv0.z;
    ov0.w = o0[rq * 4 + 3] * inv + qv0.w;
    *(float4*)(outp + base + d0) = ov0;
    float4 qv1 = *(const float4*)(query + base + 32 + d0);
    float4 ov1;
    ov1.x = o1[rq * 4 + 0] * inv + qv1.x;
    ov1.y = o1[rq * 4 + 1] * inv + qv1.y;
    ov1.z = o1[rq * 4 + 2] * inv + qv1.z;
    ov1.w = o1[rq * 4 + 3] * inv + qv1.w;
    *(float4*)(outp + base + 32 + d0) = ov1;
  }
}

extern "C" void kernel_launch(void* const* d_in, const int* in_sizes, int n_in,
                              void* d_out, int out_size, void* d_ws, size_t ws_size,
                              hipStream_t stream) {
  const float* query = (const float*)d_in[0];
  const float* key   = (const float*)d_in[1];
  const float* value = (const float*)d_in[2];
  const float* Wq = (const float*)d_in[3];
  const float* bq = (const float*)d_in[4];
  const float* Wk = (const float*)d_in[5];
  const float* bk = (const float*)d_in[6];
  const float* Wv = (const float*)d_in[7];
  const float* bv = (const float*)d_in[8];
  float* out = (float*)d_out;

  _Float16* ws = (_Float16*)d_ws;
  const size_t ACT = (size_t)Mm * Dd;
  const size_t WSZ = (size_t)Dd * Dd;
  _Float16* Wtq  = ws;
  _Float16* Wtk  = Wtq + WSZ;
  _Float16* Wtv  = Wtk + WSZ;
  _Float16* Qb   = Wtv + WSZ;
  _Float16* Kb   = Qb + ACT;
  _Float16* VtT  = Kb + ACT;   // gemm writes V^T [bh][dk][s] here directly

  cvt_wt<<<dim3(16, 16, 3), dim3(256), 0, stream>>>(Wq, Wk, Wv, Wtq, Wtk, Wtv);
  gemm_qkv<<<dim3(64, 8, 3), dim3(256), 0, stream>>>(query, key, value, Wtq, Wtk, Wtv,
                                                     bq, bk, bv, Qb, Kb, VtT);
  attn<<<dim3(64, 16), dim3(256), 0, stream>>>(Qb, Kb, VtT, query, out);
}

// Round 19
// 195.000 us; speedup vs baseline: 1.2940x; 1.0422x over previous
//
#include <hip/hip_runtime.h>
#include <hip/hip_bf16.h>
#include <stdint.h>

#define Bb 4
#define Ss 2048
#define Dd 1024
#define Hh 16
#define DK 64
#define BH 64
#define Mm 8192
#define KVT 64

typedef __attribute__((ext_vector_type(8))) _Float16 f16x8;
typedef __attribute__((ext_vector_type(4))) _Float16 f16x4;
typedef __attribute__((ext_vector_type(2))) __fp16 fp16x2;
typedef __attribute__((ext_vector_type(4))) float f32x4;
typedef __attribute__((ext_vector_type(16))) float f32x16;
typedef __attribute__((ext_vector_type(2))) unsigned uint2v;

__device__ __forceinline__ void gload16(const _Float16* g, _Float16* lds) {
  __builtin_amdgcn_global_load_lds((const __attribute__((address_space(1))) unsigned int*)g,
                                   (__attribute__((address_space(3))) unsigned int*)lds, 16, 0, 0);
}

// single v_exp_f32 (2^x). exp2f() is the libm path — the r11 regression.
#if __has_builtin(__builtin_amdgcn_exp2f)
__device__ __forceinline__ float ex2(float x) { return __builtin_amdgcn_exp2f(x); }
#else
__device__ __forceinline__ float ex2(float x) {
  float r; asm("v_exp_f32 %0, %1" : "=v"(r) : "v"(x)); return r;
}
#endif

// pack two f32 -> u32 of 2 f16 (v_cvt_pkrtz_f16_f32, 1 inst)
__device__ __forceinline__ unsigned pk2u(float a, float b) {
  union { fp16x2 h; unsigned u; } x;
  x.h = __builtin_amdgcn_cvt_pkrtz(a, b);
  return x.u;
}

// cross-half (lane ^ 32) max via permlane32_swap (VALU, not ds_bpermute)
__device__ __forceinline__ float xhalf_max(float x) {
  union { float f; unsigned u; } a; a.f = x;
  uint2v r = __builtin_amdgcn_permlane32_swap(a.u, a.u, false, false);
  union { unsigned u; float f; } b0, b1; b0.u = r[0]; b1.u = r[1];
  return fmaxf(fmaxf(x, b0.f), b1.f);
}

// ---------------- K0b: convert + transpose weights: Wt[n][k] = f16(W[k][n]) ----------------
// Q weights pre-scaled by log2(e): attention scores land in the exp2 domain.
__global__ __launch_bounds__(256) void cvt_wt(const float* __restrict__ wq,
                                              const float* __restrict__ wk,
                                              const float* __restrict__ wv,
                                              _Float16* __restrict__ tq,
                                              _Float16* __restrict__ tk,
                                              _Float16* __restrict__ tv) {
  const float* w = blockIdx.z == 0 ? wq : (blockIdx.z == 1 ? wk : wv);
  _Float16* o = blockIdx.z == 0 ? tq : (blockIdx.z == 1 ? tk : tv);
  float wscale = blockIdx.z == 0 ? 1.4426950408889634f : 1.0f;
  __shared__ float tile[64][65];
  int k0 = blockIdx.x * 64;
  int n0 = blockIdx.y * 64;
  int t = threadIdx.x;
  int tr = t >> 4;
  int tc = (t & 15) * 4;
  for (int i = 0; i < 4; i++) {
    int r = i * 16 + tr;
    float4 val = *(const float4*)(w + (k0 + r) * Dd + n0 + tc);
    tile[r][tc + 0] = val.x; tile[r][tc + 1] = val.y;
    tile[r][tc + 2] = val.z; tile[r][tc + 3] = val.w;
  }
  __syncthreads();
  for (int i = 0; i < 2; i++) {
    int vdx = t + 256 * i;
    int rn = vdx >> 3;
    int c8 = (vdx & 7) * 8;
    union { f16x8 v8; _Float16 h[8]; } o2;
    for (int j = 0; j < 8; j++) o2.h[j] = (_Float16)(tile[c8 + j][rn] * wscale);
    *(f16x8*)(o + (n0 + rn) * Dd + k0 + c8) = o2.v8;
  }
}

// ---------------- K1: projection GEMM — double-buffered + XOR-swizzled LDS ----------------
// A = raw fp32 activation, fused-converted during staging (reg load -> cvt_pkrtz ->
// swizzled-content ds_write); B = f16 weights^T via global_load_lds with PRE-SWIZZLED
// global source (LDS linear, rule #21). Both read at slot^(row&7) -> attn-level conflicts.
// K-loop double-buffered: prefetch t+1 issued before compute t, one barrier per step
// (the r7/r17 attn schedule). Q,K out [bh][s][dk]; V out TRANSPOSED [bh][dk][s].
__global__ __launch_bounds__(256) void gemm_qkv(
    const float* __restrict__ aq, const float* __restrict__ ak,
    const float* __restrict__ av,
    const _Float16* __restrict__ wtq, const _Float16* __restrict__ wtk,
    const _Float16* __restrict__ wtv,
    const float* __restrict__ bq, const float* __restrict__ bk, const float* __restrict__ bv,
    _Float16* __restrict__ oq, _Float16* __restrict__ ok,
    _Float16* __restrict__ ov) {
  int z = blockIdx.z;
  const float* Af    = z == 0 ? aq  : (z == 1 ? ak  : av);
  const _Float16* Bt = z == 0 ? wtq : (z == 1 ? wtk : wtv);
  const float* bias  = z == 0 ? bq  : (z == 1 ? bk  : bv);
  _Float16* out      = z == 0 ? oq  : (z == 1 ? ok  : ov);
  float bscale       = z == 0 ? 1.4426950408889634f : 1.0f;

  __shared__ _Float16 As[2][128 * 64];
  __shared__ _Float16 Bs[2][128 * 64];

  int tid = threadIdx.x;
  int w = tid >> 6;
  int l = tid & 63;
  int lr = l & 15, lk = l >> 4;
  int m0 = blockIdx.x * 128;
  int n0 = blockIdx.y * 128;
  int wr = (w >> 1) * 64;
  int wc = (w & 1) * 64;

  // staging geometry: lane l covers rows i*32 + w*8 + srow; LDS slot l&7 (linear),
  // swizzled global source slot cs = (l&7) ^ srow  (srow = row&7 for all i)
  int srow = l >> 3;
  int cs = (l & 7) ^ srow;
  const float*    ap[4];
  const _Float16* bp[4];
#pragma unroll
  for (int i = 0; i < 4; i++) {
    int row = i * 32 + w * 8 + srow;
    ap[i] = Af + (size_t)(m0 + row) * Dd + cs * 8;
    bp[i] = Bt + (size_t)(n0 + row) * Dd + cs * 8;
  }

  f32x4 acc[4][4] = {};
  int lr7 = lr & 7;
  int rs0 = (lk ^ lr7) * 8;         // kh=0 swizzled slot (element offset)
  int rs1 = ((4 + lk) ^ lr7) * 8;   // kh=1

#define ALOAD(AR)                                                         \
  _Pragma("unroll")                                                       \
  for (int i = 0; i < 4; i++) {                                           \
    AR[i][0] = *(const float4*)(ap[i]);                                   \
    AR[i][1] = *(const float4*)(ap[i] + 4);                               \
    ap[i] += 64;                                                          \
  }
#define BDMA(NXT)                                                         \
  _Pragma("unroll")                                                       \
  for (int i = 0; i < 4; i++) {                                           \
    gload16(bp[i], &Bs[NXT][(i * 256 + w * 64) * 8]);                     \
    bp[i] += 64;                                                          \
  }
#define AWRITE(AR, NXT)                                                   \
  _Pragma("unroll")                                                       \
  for (int i = 0; i < 4; i++) {                                           \
    union { unsigned u[4]; f16x8 v; } aw;                                 \
    aw.u[0] = pk2u(AR[i][0].x, AR[i][0].y);                               \
    aw.u[1] = pk2u(AR[i][0].z, AR[i][0].w);                               \
    aw.u[2] = pk2u(AR[i][1].x, AR[i][1].y);                               \
    aw.u[3] = pk2u(AR[i][1].z, AR[i][1].w);                               \
    *(f16x8*)&As[NXT][(i * 256 + w * 64 + l) * 8] = aw.v;                 \
  }
#define GCOMP(CUR)                                                              \
  _Pragma("unroll")                                                             \
  for (int kh = 0; kh < 2; kh++) {                                              \
    int rs = kh ? rs1 : rs0;                                                    \
    f16x8 af[4], bf[4];                                                         \
    _Pragma("unroll")                                                           \
    for (int mi = 0; mi < 4; mi++)                                              \
      af[mi] = *(const f16x8*)&As[CUR][(wr + mi * 16 + lr) * 64 + rs];          \
    _Pragma("unroll")                                                           \
    for (int ni = 0; ni < 4; ni++)                                              \
      bf[ni] = *(const f16x8*)&Bs[CUR][(wc + ni * 16 + lr) * 64 + rs];          \
    _Pragma("unroll")                                                           \
    for (int mi = 0; mi < 4; mi++)                                              \
      _Pragma("unroll")                                                         \
      for (int ni = 0; ni < 4; ni++)                                            \
        acc[mi][ni] = __builtin_amdgcn_mfma_f32_16x16x32_f16(af[mi], bf[ni], acc[mi][ni], 0, 0, 0); \
  }

  // prologue: stage K-tile 0 into buf0
  {
    float4 ar[4][2];
    ALOAD(ar)
    BDMA(0)
    AWRITE(ar, 0)
  }
  __syncthreads();

  // 7 double-steps (tiles 0..13) + tail (14 with prefetch 15, then 15)
  for (int it = 0; it < 7; ++it) {
    {
      float4 ar[4][2];
      ALOAD(ar)
      BDMA(1)
      GCOMP(0)
      AWRITE(ar, 1)
    }
    __syncthreads();
    {
      float4 ar[4][2];
      ALOAD(ar)
      BDMA(0)
      GCOMP(1)
      AWRITE(ar, 0)
    }
    __syncthreads();
  }
  {
    float4 ar[4][2];
    ALOAD(ar)
    BDMA(1)
    GCOMP(0)
    AWRITE(ar, 1)
  }
  __syncthreads();
  GCOMP(1)
#undef GCOMP
#undef AWRITE
#undef BDMA
#undef ALOAD

  if (z == 2) {
    // V^T epilogue: lane holds 4 consecutive s for fixed dk -> one aligned 8B store
    for (int mi = 0; mi < 4; mi++) {
      for (int ni = 0; ni < 4; ni++) {
        int n = n0 + wc + ni * 16 + lr;
        float bval = bias[n];
        int h = n >> 6, dk = n & 63;
        int m = m0 + wr + mi * 16 + lk * 4;
        int b = m >> 11, s = m & 2047;
        f16x4 o4;
        for (int j = 0; j < 4; j++) o4[j] = (_Float16)(acc[mi][ni][j] + bval);
        *(f16x4*)(out + ((size_t)((b * Hh + h) * DK + dk) * Ss + s)) = o4;
      }
    }
  } else {
    for (int mi = 0; mi < 4; mi++) {
      for (int ni = 0; ni < 4; ni++) {
        int n = n0 + wc + ni * 16 + lr;
        float bval = bias[n] * bscale;
        int h = n >> 6, dk = n & 63;
        for (int j = 0; j < 4; j++) {
          int m = m0 + wr + mi * 16 + lk * 4 + j;
          int b = m >> 11, s = m & 2047;
          out[((b * Hh + h) * Ss + s) * DK + dk] = (_Float16)(acc[mi][ni][j] + bval);
        }
      }
    }
  }
}

// ---------------- K3: flash attention, 32x32x16, LDS dbuf K/V, kv-loop unrolled x2 (r17, 121us) ----------------
__global__ __launch_bounds__(256) void attn(const _Float16* __restrict__ Qb,
                                            const _Float16* __restrict__ Kb,
                                            const _Float16* __restrict__ Vt,
                                            const float* __restrict__ query,
                                            float* __restrict__ outp) {
  __shared__ _Float16 Kl[2][KVT * 64];
  __shared__ _Float16 Vl[2][KVT * 64];

  int tid = threadIdx.x;
  int w = tid >> 6, l = tid & 63;
  int l31 = l & 31, hi = l >> 5;
  int bh = blockIdx.x;
  int q0 = blockIdx.y * 128 + w * 32;
  const _Float16* Qp = Qb + bh * (Ss * DK);
  const _Float16* Kp = Kb + bh * (Ss * DK);
  const _Float16* Vp = Vt + bh * (DK * Ss);

  // staging: lane l -> row base+(l>>3), LDS slot l&7; global slot = (l&7)^(row&7)
  int srow = l >> 3;
  int sslot = (l & 7) ^ (srow & 7);
  int w16 = w * 16;
  // running stage pointers (strength-reduced; advanced after each STAGE)
  const _Float16* kp0 = Kp + (w16 + srow) * DK + sslot * 8;
  const _Float16* kp1 = Kp + (w16 + 8 + srow) * DK + sslot * 8;
  const _Float16* vp0 = Vp + (w16 + srow) * Ss + sslot * 8;
  const _Float16* vp1 = Vp + (w16 + 8 + srow) * Ss + sslot * 8;

#define STAGE(BUF)                                                        \
  {                                                                       \
    gload16(kp0, &Kl[BUF][w16 * 64]);                                     \
    gload16(kp1, &Kl[BUF][(w16 + 8) * 64]);                               \
    gload16(vp0, &Vl[BUF][w16 * 64]);                                     \
    gload16(vp1, &Vl[BUF][(w16 + 8) * 64]);                               \
    kp0 += KVT * DK; kp1 += KVT * DK; vp0 += KVT; vp1 += KVT;             \
  }

  // Q as B-operand: col=q=q0+l31, k=dk=s*16+hi*8+i
  f16x8 qf[4];
#pragma unroll
  for (int s = 0; s < 4; s++)
    qf[s] = *(const f16x8*)(Qp + (q0 + l31) * DK + s * 16 + hi * 8);

  f32x16 o0 = {}, o1 = {};    // ctx^T: row d=dg*32+(r&3)+8*(r>>2)+4*hi, col q=l31
  float mrun = -1e30f, lrun = 0.f;   // lrun is LANE-PARTIAL (this half's sum)

  // swizzled LDS read slots: slot = ((s*2+hi) ^ (row&7)), row&7 == l31&7 for our reads
  int kv7 = l31 & 7;
  int rslot[4];
#pragma unroll
  for (int s = 0; s < 4; s++) rslot[s] = ((s * 2 + hi) ^ kv7) * 8;

  // TILE: full per-tile compute on compile-time buffer BUF
#define TILE(BUF)                                                               \
  {                                                                             \
    f32x16 s0 = {}, s1 = {};                                                    \
    _Pragma("unroll")                                                           \
    for (int s = 0; s < 4; s++) {                                               \
      f16x8 ka = *(const f16x8*)&Kl[BUF][l31 * 64 + rslot[s]];                  \
      s0 = __builtin_amdgcn_mfma_f32_32x32x16_f16(ka, qf[s], s0, 0, 0, 0);      \
    }                                                                           \
    _Pragma("unroll")                                                           \
    for (int s = 0; s < 4; s++) {                                               \
      f16x8 kb = *(const f16x8*)&Kl[BUF][(32 + l31) * 64 + rslot[s]];           \
      s1 = __builtin_amdgcn_mfma_f32_32x32x16_f16(kb, qf[s], s1, 0, 0, 0);      \
    }                                                                           \
    float m8[8];                                                                \
    _Pragma("unroll")                                                           \
    for (int r = 0; r < 8; r++)                                                 \
      m8[r] = fmaxf(fmaxf(s0[r], s0[r + 8]), fmaxf(s1[r], s1[r + 8]));          \
    _Pragma("unroll")                                                           \
    for (int d = 4; d >= 1; d >>= 1)                                            \
      for (int r = 0; r < 4; r++) if (r < d) m8[r] = fmaxf(m8[r], m8[r + d]);   \
    float pm = xhalf_max(m8[0]);                                                \
    if (!__all(pm - mrun <= 8.f)) {   /* defer-max (T13), log2 units */         \
      float mn = fmaxf(mrun, pm);                                               \
      float sc_ = ex2(mrun - mn);                                               \
      mrun = mn;                                                                \
      lrun *= sc_;                                                              \
      _Pragma("unroll")                                                         \
      for (int r = 0; r < 16; r++) { o0[r] *= sc_; o1[r] *= sc_; }              \
    }                                                                           \
    _Pragma("unroll")                                                           \
    for (int r = 0; r < 16; r++) {                                              \
      s0[r] = ex2(s0[r] - mrun);                                                \
      s1[r] = ex2(s1[r] - mrun);                                                \
    }                                                                           \
    float s8[8];                                                                \
    _Pragma("unroll")                                                           \
    for (int r = 0; r < 8; r++) s8[r] = (s0[r] + s0[r + 8]) + (s1[r] + s1[r + 8]); \
    _Pragma("unroll")                                                           \
    for (int d = 4; d >= 1; d >>= 1)                                            \
      for (int r = 0; r < 4; r++) if (r < d) s8[r] += s8[r + d];                \
    lrun += s8[0];                                                              \
    PVSTEP(BUF, s0, 0, 0)                                                       \
    PVSTEP(BUF, s0, 8, 1)                                                       \
    PVSTEP(BUF, s1, 0, 2)                                                       \
    PVSTEP(BUF, s1, 8, 3)                                                       \
  }

#define PVSTEP(BUF, SRC, OFF, KST)                                              \
    {                                                                           \
      unsigned a0 = pk2u(SRC[(OFF) + 0], SRC[(OFF) + 1]);                       \
      unsigned a1 = pk2u(SRC[(OFF) + 2], SRC[(OFF) + 3]);                       \
      unsigned b0 = pk2u(SRC[(OFF) + 4], SRC[(OFF) + 5]);                       \
      unsigned b1 = pk2u(SRC[(OFF) + 6], SRC[(OFF) + 7]);                       \
      uint2v r0 = __builtin_amdgcn_permlane32_swap(a0, b0, false, false);       \
      uint2v r1 = __builtin_amdgcn_permlane32_swap(a1, b1, false, false);       \
      union { unsigned u[4]; f16x8 v; } pf;                                     \
      pf.u[0] = r0[0]; pf.u[1] = r1[0]; pf.u[2] = r0[1]; pf.u[3] = r1[1];       \
      f16x8 v0 = *(const f16x8*)&Vl[BUF][l31 * 64 + rslot[KST]];                \
      f16x8 v1 = *(const f16x8*)&Vl[BUF][(32 + l31) * 64 + rslot[KST]];         \
      o0 = __builtin_amdgcn_mfma_f32_32x32x16_f16(v0, pf.v, o0, 0, 0, 0);       \
      o1 = __builtin_amdgcn_mfma_f32_32x32x16_f16(v1, pf.v, o1, 0, 0, 0);       \
    }

  STAGE(0)
  __syncthreads();

  // 15 double-tiles with full prefetch, then the final pair (no stage past end)
  for (int it = 0; it < 15; ++it) {
    STAGE(1)
    TILE(0)
    __syncthreads();
    STAGE(0)
    TILE(1)
    __syncthreads();
  }
  STAGE(1)
  TILE(0)
  __syncthreads();
  TILE(1)
#undef PVSTEP
#undef TILE
#undef STAGE

  // ---- epilogue: reduce lane-partial lrun, normalize, add residual ----
  lrun += __shfl_xor(lrun, 32);
  int b = bh >> 4, h = bh & 15;
  float inv = 1.f / lrun;
  int base = (b * Ss + q0 + l31) * Dd + h * 64;
#pragma unroll
  for (int rq = 0; rq < 4; rq++) {
    int d0 = rq * 8 + hi * 4;
    float4 qv0 = *(const float4*)(query + base + d0);
    float4 ov0;
    ov0.x = o0[rq * 4 + 0] * inv + qv0.x;
    ov0.y = o0[rq * 4 + 1] * inv + qv0.y;
    ov0.z = o0[rq * 4 + 2] * inv + qv0.z;
    ov0.w = o0[rq * 4 + 3] * inv + qv0.w;
    *(float4*)(outp + base + d0) = ov0;
    float4 qv1 = *(const float4*)(query + base + 32 + d0);
    float4 ov1;
    ov1.x = o1[rq * 4 + 0] * inv + qv1.x;
    ov1.y = o1[rq * 4 + 1] * inv + qv1.y;
    ov1.z = o1[rq * 4 + 2] * inv + qv1.z;
    ov1.w = o1[rq * 4 + 3] * inv + qv1.w;
    *(float4*)(outp + base + 32 + d0) = ov1;
  }
}

extern "C" void kernel_launch(void* const* d_in, const int* in_sizes, int n_in,
                              void* d_out, int out_size, void* d_ws, size_t ws_size,
                              hipStream_t stream) {
  const float* query = (const float*)d_in[0];
  const float* key   = (const float*)d_in[1];
  const float* value = (const float*)d_in[2];
  const float* Wq = (const float*)d_in[3];
  const float* bq = (const float*)d_in[4];
  const float* Wk = (const float*)d_in[5];
  const float* bk = (const float*)d_in[6];
  const float* Wv = (const float*)d_in[7];
  const float* bv = (const float*)d_in[8];
  float* out = (float*)d_out;

  _Float16* ws = (_Float16*)d_ws;
  const size_t ACT = (size_t)Mm * Dd;
  const size_t WSZ = (size_t)Dd * Dd;
  _Float16* Wtq  = ws;
  _Float16* Wtk  = Wtq + WSZ;
  _Float16* Wtv  = Wtk + WSZ;
  _Float16* Qb   = Wtv + WSZ;
  _Float16* Kb   = Qb + ACT;
  _Float16* VtT  = Kb + ACT;   // gemm writes V^T [bh][dk][s] here directly

  cvt_wt<<<dim3(16, 16, 3), dim3(256), 0, stream>>>(Wq, Wk, Wv, Wtq, Wtk, Wtv);
  gemm_qkv<<<dim3(64, 8, 3), dim3(256), 0, stream>>>(query, key, value, Wtq, Wtk, Wtv,
                                                     bq, bk, bv, Qb, Kb, VtT);
  attn<<<dim3(64, 16), dim3(256), 0, stream>>>(Qb, Kb, VtT, query, out);
}